// Round 1
// baseline (3129.797 us; speedup 1.0000x reference)
//
#include <hip/hip_runtime.h>
#include <hip/hip_bf16.h>
#include <math.h>
#include <stdint.h>

// Problem constants
constexpr int Lc  = 4;
constexpr int Bc  = 2;
constexpr int Sc  = 2048;
constexpr int Dc  = 1024;
constexpr int Hc  = 16;
constexpr int Vc  = 50257;
constexpr int Fc  = 4096;
constexpr int DHc = 64;
constexpr int Mr  = Bc * Sc;       // 4096 token rows
constexpr int QKVN = 3 * Dc;       // 3072 fused QKV width
constexpr int Vpad = 50304;        // vocab padded to 128*393
constexpr int NVT  = Vpad / 128;   // 393 vocab tiles
constexpr int NQT  = Sc / 128;     // 16 q-tiles per (b,h)

typedef __attribute__((ext_vector_type(8))) short short8;   // 8 bf16 (4 VGPRs)
typedef __attribute__((ext_vector_type(4))) float f32x4;

// async global->LDS, 16 B per lane; LDS dest must be wave-uniform base + lane*16
__device__ __forceinline__ void gl2lds16(const __hip_bfloat16* g, __hip_bfloat16* l) {
    __builtin_amdgcn_global_load_lds(
        (const uint32_t __attribute__((address_space(1)))*)g,
        (uint32_t __attribute__((address_space(3)))*)l, 16, 0, 0);
}

__device__ __forceinline__ void lse_combine(float& m, float& s, float mo, float so) {
    float mn = fmaxf(m, mo);
    s = s * expf(m - mn) + so * expf(mo - mn);
    m = mn;
}

// ---------------------------------------------------------------------------
// Embedding
// ---------------------------------------------------------------------------
__global__ void embed_kernel(const int* __restrict__ tokens,
                             const float* __restrict__ we,
                             const float* __restrict__ pe,
                             float* __restrict__ x) {
    int row = blockIdx.x;
    int s   = row & (Sc - 1);
    int tok = tokens[row];
    const float* wp = we + (size_t)tok * Dc;
    const float* pp = pe + (size_t)s * Dc;
    float* xp = x + (size_t)row * Dc;
    for (int i = threadIdx.x; i < Dc; i += blockDim.x)
        xp[i] = wp[i] + pp[i];
}

// ---------------------------------------------------------------------------
// LayerNorm; optional fp32 and/or bf16 outputs. Safe in-place for outF==x.
// ---------------------------------------------------------------------------
__global__ __launch_bounds__(256) void ln_kernel(const float* __restrict__ x,
                                                 const float* __restrict__ w,
                                                 const float* __restrict__ b,
                                                 float* __restrict__ outF,
                                                 __hip_bfloat16* __restrict__ outB) {
    __shared__ float red[256];
    int row = blockIdx.x;
    int tid = threadIdx.x;
    const float* xp = x + (size_t)row * Dc;
    float s1 = 0.f, s2 = 0.f;
    for (int i = tid; i < Dc; i += 256) {
        float v = xp[i];
        s1 += v; s2 += v * v;
    }
    red[tid] = s1; __syncthreads();
    for (int off = 128; off > 0; off >>= 1) {
        if (tid < off) red[tid] += red[tid + off];
        __syncthreads();
    }
    float mean = red[0] * (1.0f / Dc);
    __syncthreads();
    red[tid] = s2; __syncthreads();
    for (int off = 128; off > 0; off >>= 1) {
        if (tid < off) red[tid] += red[tid + off];
        __syncthreads();
    }
    float var  = red[0] * (1.0f / Dc) - mean * mean;
    float rstd = rsqrtf(var + 1e-5f);
    for (int i = tid; i < Dc; i += 256) {
        float v = (xp[i] - mean) * rstd * w[i] + b[i];
        if (outF) outF[(size_t)row * Dc + i] = v;
        if (outB) outB[(size_t)row * Dc + i] = __float2bfloat16(v);
    }
}

// ---------------------------------------------------------------------------
// Weight transpose + bf16 convert: W [K][srcN] f32 -> Wt [dstN][K] bf16,
// rows >= srcN zero-filled. Grid (dstN/32, K/32), block 256.
// ---------------------------------------------------------------------------
__global__ __launch_bounds__(256) void convw_kernel(const float* __restrict__ W,
                                                    __hip_bfloat16* __restrict__ Wt,
                                                    int K, int srcN) {
    __shared__ float t[32][33];
    int n0 = blockIdx.x * 32, k0 = blockIdx.y * 32;
    int tx = threadIdx.x & 31, ty = threadIdx.x >> 5;
    #pragma unroll
    for (int j = 0; j < 4; j++) {
        int k = k0 + ty + j * 8, n = n0 + tx;
        t[ty + j * 8][tx] = (n < srcN) ? W[(size_t)k * srcN + n] : 0.f;
    }
    __syncthreads();
    #pragma unroll
    for (int j = 0; j < 4; j++) {
        int n = n0 + ty + j * 8, k = k0 + tx;
        Wt[(size_t)n * K + k] = __float2bfloat16(t[tx][ty + j * 8]);
    }
}

__global__ void bcat_kernel(const float* __restrict__ bq, const float* __restrict__ bk,
                            const float* __restrict__ bv, float* __restrict__ o) {
    int i = blockIdx.x * 256 + threadIdx.x;
    if (i < QKVN)
        o[i] = (i < Dc) ? bq[i] : (i < 2 * Dc) ? bk[i - Dc] : bv[i - 2 * Dc];
}

// ---------------------------------------------------------------------------
// bf16 MFMA GEMM (m97 structure): C = act(A @ Bt^T + bias [+ Cin]).
// A [M][K] bf16, Bt [N][K] bf16 (i.e. B transposed). Tile 128x128, BK=32.
// Outputs fp32 (outF) and/or bf16 (outB). M,N mult of 128, K mult of 32.
// ---------------------------------------------------------------------------
__global__ __launch_bounds__(256) void bgemm_kernel(
    const __hip_bfloat16* __restrict__ A,
    const __hip_bfloat16* __restrict__ Bt,
    const float* __restrict__ bias,
    const float* __restrict__ Cin,
    float* __restrict__ outF,
    __hip_bfloat16* __restrict__ outB,
    int N, int K, int act) {
    __shared__ __align__(16) __hip_bfloat16 As[128 * 32];
    __shared__ __align__(16) __hip_bfloat16 Bs[128 * 32];
    const int tid = threadIdx.x;
    const int rowBase = blockIdx.y * 128;
    const int colBase = blockIdx.x * 128;
    const int w = tid >> 6, lane = tid & 63;
    const int wm = w >> 1, wn = w & 1;
    const int quad = lane >> 4, l16 = lane & 15;

    f32x4 acc[4][4];
    #pragma unroll
    for (int i = 0; i < 4; i++)
        #pragma unroll
        for (int j = 0; j < 4; j++) acc[i][j] = (f32x4){0.f, 0.f, 0.f, 0.f};

    const __hip_bfloat16* a0 = A  + (size_t)(rowBase + (tid >> 2)) * K + (tid & 3) * 8;
    const __hip_bfloat16* b0 = Bt + (size_t)(colBase + (tid >> 2)) * K + (tid & 3) * 8;
    const size_t rstep = (size_t)64 * K;
    __hip_bfloat16* lA = As + tid * 8;
    __hip_bfloat16* lB = Bs + tid * 8;

    for (int k0 = 0; k0 < K; k0 += 32) {
        __syncthreads();
        gl2lds16(a0 + k0,         lA);
        gl2lds16(a0 + k0 + rstep, lA + 2048);
        gl2lds16(b0 + k0,         lB);
        gl2lds16(b0 + k0 + rstep, lB + 2048);
        __syncthreads();

        short8 af[4], bf[4];
        #pragma unroll
        for (int i = 0; i < 4; i++) {
            af[i] = *(const short8*)(As + (wm * 64 + i * 16 + l16) * 32 + quad * 8);
            bf[i] = *(const short8*)(Bs + (wn * 64 + i * 16 + l16) * 32 + quad * 8);
        }
        #pragma unroll
        for (int i = 0; i < 4; i++)
            #pragma unroll
            for (int j = 0; j < 4; j++)
                acc[i][j] = __builtin_amdgcn_mfma_f32_16x16x32_bf16(af[i], bf[j], acc[i][j], 0, 0, 0);
    }

    #pragma unroll
    for (int i = 0; i < 4; i++) {
        #pragma unroll
        for (int j = 0; j < 4; j++) {
            int col = colBase + wn * 64 + j * 16 + l16;
            float bb = bias ? bias[col] : 0.f;
            #pragma unroll
            for (int r = 0; r < 4; r++) {
                int row = rowBase + wm * 64 + i * 16 + quad * 4 + r;
                float v = acc[i][j][r] + bb;
                if (Cin) v += Cin[(size_t)row * N + col];
                if (act) v = 0.5f * v * (1.0f + erff(v * 0.70710678118654752f));
                if (outF) outF[(size_t)row * N + col] = v;
                if (outB) outB[(size_t)row * N + col] = __float2bfloat16(v);
            }
        }
    }
}

// ---------------------------------------------------------------------------
// Head GEMM (same core) with fused per-row partial logsumexp over the block's
// 128 vocab cols + target-logit capture. Logits never hit global memory.
// Grid (NVT, Mr/128). Partials: pmax/psum [NVT][Mr].
// ---------------------------------------------------------------------------
__global__ __launch_bounds__(256) void headgemm_kernel(
    const __hip_bfloat16* __restrict__ A,
    const __hip_bfloat16* __restrict__ Bt,
    const int* __restrict__ targets,
    float* __restrict__ pmax, float* __restrict__ psum,
    float* __restrict__ tlog) {
    __shared__ __align__(16) __hip_bfloat16 As[128 * 32];
    __shared__ __align__(16) __hip_bfloat16 Bs[128 * 32];
    __shared__ float pmW[2][128], psW[2][128];
    __shared__ int tg[128];
    const int tid = threadIdx.x;
    const int rowBase = blockIdx.y * 128;
    const int colBase = blockIdx.x * 128;
    const int K = Dc;
    const int w = tid >> 6, lane = tid & 63;
    const int wm = w >> 1, wn = w & 1;
    const int quad = lane >> 4, l16 = lane & 15;

    if (tid < 128) tg[tid] = targets[rowBase + tid];

    f32x4 acc[4][4];
    #pragma unroll
    for (int i = 0; i < 4; i++)
        #pragma unroll
        for (int j = 0; j < 4; j++) acc[i][j] = (f32x4){0.f, 0.f, 0.f, 0.f};

    const __hip_bfloat16* a0 = A  + (size_t)(rowBase + (tid >> 2)) * K + (tid & 3) * 8;
    const __hip_bfloat16* b0 = Bt + (size_t)(colBase + (tid >> 2)) * K + (tid & 3) * 8;
    const size_t rstep = (size_t)64 * K;
    __hip_bfloat16* lA = As + tid * 8;
    __hip_bfloat16* lB = Bs + tid * 8;

    for (int k0 = 0; k0 < K; k0 += 32) {
        __syncthreads();
        gl2lds16(a0 + k0,         lA);
        gl2lds16(a0 + k0 + rstep, lA + 2048);
        gl2lds16(b0 + k0,         lB);
        gl2lds16(b0 + k0 + rstep, lB + 2048);
        __syncthreads();

        short8 af[4], bf[4];
        #pragma unroll
        for (int i = 0; i < 4; i++) {
            af[i] = *(const short8*)(As + (wm * 64 + i * 16 + l16) * 32 + quad * 8);
            bf[i] = *(const short8*)(Bs + (wn * 64 + i * 16 + l16) * 32 + quad * 8);
        }
        #pragma unroll
        for (int i = 0; i < 4; i++)
            #pragma unroll
            for (int j = 0; j < 4; j++)
                acc[i][j] = __builtin_amdgcn_mfma_f32_16x16x32_bf16(af[i], bf[j], acc[i][j], 0, 0, 0);
    }

    #pragma unroll
    for (int i = 0; i < 4; i++) {
        #pragma unroll
        for (int r = 0; r < 4; r++) {
            int rib = wm * 64 + i * 16 + quad * 4 + r;
            float m = -1e30f, s = 0.f;
            float vals[4];
            #pragma unroll
            for (int j = 0; j < 4; j++) {
                int col = colBase + wn * 64 + j * 16 + l16;
                float v = acc[i][j][r];
                bool ok = (col < Vc);
                if (ok && col == tg[rib]) tlog[rowBase + rib] = v;
                vals[j] = ok ? v : -1e30f;
                m = fmaxf(m, vals[j]);
            }
            #pragma unroll
            for (int j = 0; j < 4; j++) s += expf(vals[j] - m);  // masked -> underflow 0
            #pragma unroll
            for (int d = 1; d < 16; d <<= 1) {
                float mo = __shfl_xor(m, d, 64);
                float so = __shfl_xor(s, d, 64);
                lse_combine(m, s, mo, so);
            }
            if (l16 == 0) { pmW[wn][rib] = m; psW[wn][rib] = s; }
        }
    }
    __syncthreads();
    if (tid < 128) {
        float m = pmW[0][tid], s = psW[0][tid];
        lse_combine(m, s, pmW[1][tid], psW[1][tid]);
        pmax[(size_t)blockIdx.x * Mr + rowBase + tid] = m;
        psum[(size_t)blockIdx.x * Mr + rowBase + tid] = s;
    }
}

__global__ __launch_bounds__(256) void head_reduce_kernel(
    const float* __restrict__ pmax, const float* __restrict__ psum,
    const float* __restrict__ tlog, float* __restrict__ nll) {
    __shared__ float rm[256], rs[256];
    int row = blockIdx.x;
    int tid = threadIdx.x;
    float m = -1e30f, s = 0.f;
    for (int t = tid; t < NVT; t += 256)
        lse_combine(m, s, pmax[(size_t)t * Mr + row], psum[(size_t)t * Mr + row]);
    rm[tid] = m; rs[tid] = s; __syncthreads();
    for (int off = 128; off > 0; off >>= 1) {
        if (tid < off) {
            float mm = rm[tid], ss = rs[tid];
            lse_combine(mm, ss, rm[tid + off], rs[tid + off]);
            rm[tid] = mm; rs[tid] = ss;
        }
        __syncthreads();
    }
    if (tid == 0) nll[row] = rm[0] + logf(rs[0]) - tlog[row];
}

// ---------------------------------------------------------------------------
// RoPE + bf16 split: reads fused bf16 qkv [Mr][3072]; writes
// qb [B*H][S][64] (pre-scaled by 1/sqrt(DH)) and kb [B*H][S][64].
// ---------------------------------------------------------------------------
__global__ void ropecvt_kernel(const __hip_bfloat16* __restrict__ qkvb,
                               __hip_bfloat16* __restrict__ qb,
                               __hip_bfloat16* __restrict__ kb) {
    int p = blockIdx.x * blockDim.x + threadIdx.x;
    if (p >= Mr * Hc * 32) return;
    int j    = p & 31;
    int h    = (p >> 5) & (Hc - 1);
    int srow = p >> 9;
    int s    = srow & (Sc - 1);
    int b    = srow >> 11;
    float inv = powf(10000.0f, -(float)(2 * j) * (1.0f / 64.0f));
    float fr  = (float)s * inv;
    float c = cosf(fr), sn = sinf(fr);
    size_t base = (size_t)srow * QKVN + h * DHc;
    size_t o = ((size_t)(b * Hc + h) * Sc + s) * DHc;
    float q1 = __bfloat162float(qkvb[base + j]);
    float q2 = __bfloat162float(qkvb[base + j + 32]);
    qb[o + j]      = __float2bfloat16((q1 * c - q2 * sn) * 0.125f);
    qb[o + j + 32] = __float2bfloat16((q2 * c + q1 * sn) * 0.125f);
    float k1 = __bfloat162float(qkvb[base + Dc + j]);
    float k2 = __bfloat162float(qkvb[base + Dc + j + 32]);
    kb[o + j]      = __float2bfloat16(k1 * c - k2 * sn);
    kb[o + j + 32] = __float2bfloat16(k2 * c + k1 * sn);
}

// ---------------------------------------------------------------------------
// V transpose: fused qkv [Mr][3072] bf16 -> vtb [B*H][64][S] bf16.
// Grid (S/32, DH/32, B*H), block 256, LDS-tiled.
// ---------------------------------------------------------------------------
__global__ __launch_bounds__(256) void vt_kernel(const __hip_bfloat16* __restrict__ qkvb,
                                                 __hip_bfloat16* __restrict__ vtb) {
    __shared__ float t[32][33];
    int s0 = blockIdx.x * 32, d0 = blockIdx.y * 32;
    int bh = blockIdx.z;
    int b = bh >> 4, h = bh & (Hc - 1);
    int tx = threadIdx.x & 31, ty = threadIdx.x >> 5;
    #pragma unroll
    for (int jj = 0; jj < 4; jj++) {
        int s = s0 + ty + jj * 8;
        t[ty + jj * 8][tx] = __bfloat162float(
            qkvb[((size_t)(b * Sc + s)) * QKVN + 2 * Dc + h * DHc + d0 + tx]);
    }
    __syncthreads();
    #pragma unroll
    for (int jj = 0; jj < 4; jj++) {
        int d = d0 + ty + jj * 8;
        vtb[((size_t)bh * DHc + d) * Sc + s0 + tx] = __float2bfloat16(t[tx][ty + jj * 8]);
    }
}

// ---------------------------------------------------------------------------
// Flash attention, MFMA. One block per (b,h,qtile): 512 blocks, 4 waves.
// Wave w owns q-rows [w*32, w*32+32); full 128-col K tile per wave so the
// online softmax reduces purely intra-wave (shfl over l16 bits).
// K tile [128][64] and Vt tile [64][128] staged via global_load_lds with
// pre-swizzled global source (chunk ^= row&7) so swizzled ds_read_b128 is
// bank-conflict-free (G4/T2). P round-trips through wave-private swizzled
// LDS rows to convert D-frag layout -> A-frag layout.
// ---------------------------------------------------------------------------
__global__ __launch_bounds__(256) void attn_mfma_kernel(
    const __hip_bfloat16* __restrict__ qb,
    const __hip_bfloat16* __restrict__ kb,
    const __hip_bfloat16* __restrict__ vtb,
    __hip_bfloat16* __restrict__ ob) {
    __shared__ __align__(16) __hip_bfloat16 Ks[128 * 64];    // 16 KB
    __shared__ __align__(16) __hip_bfloat16 Vts[64 * 128];   // 16 KB
    __shared__ __align__(16) __hip_bfloat16 Ps[128 * 128];   // 32 KB

    const int tid  = threadIdx.x;
    const int idx  = blockIdx.x;
    const int qt   = (NQT - 1) - (idx >> 5);   // heavy q-tiles dispatch first (LPT)
    const int bh   = idx & 31;
    const int b    = bh >> 4, h = bh & (Hc - 1);
    const int w    = tid >> 6, lane = tid & 63;
    const int quad = lane >> 4, l16 = lane & 15;
    const int sz   = l16 & 7;                  // row&7 swizzle term for l16-mapped rows

    const __hip_bfloat16* kb_bh = kb  + (size_t)bh * Sc * DHc;
    const __hip_bfloat16* vt_bh = vtb + (size_t)bh * DHc * Sc;

    // Q fragments held in registers for the whole block (A-frag: row=l16, k=quad*8+j)
    short8 afq[2][2];
    {
        const __hip_bfloat16* qp =
            qb + ((size_t)bh * Sc + qt * 128 + w * 32 + l16) * DHc;
        #pragma unroll
        for (int i = 0; i < 2; i++)
            #pragma unroll
            for (int dc = 0; dc < 2; dc++)
                afq[i][dc] = *(const short8*)(qp + i * 16 * DHc + (dc * 4 + quad) * 8);
    }

    f32x4 oacc[2][4];
    float m[2][4], lsum[2][4];
    #pragma unroll
    for (int i = 0; i < 2; i++)
        #pragma unroll
        for (int dt = 0; dt < 4; dt++) oacc[i][dt] = (f32x4){0.f, 0.f, 0.f, 0.f};
    #pragma unroll
    for (int i = 0; i < 2; i++)
        #pragma unroll
        for (int r = 0; r < 4; r++) { m[i][r] = -1e30f; lsum[i][r] = 0.f; }

    for (int kt = 0; kt <= qt; ++kt) {
        __syncthreads();   // all waves done reading Ks/Vts of previous tile
        // stage K tile: LDS linear, global source pre-swizzled (chunk ^ (k&7))
        #pragma unroll
        for (int p = 0; p < 4; p++) {
            int k = p * 32 + (tid >> 3);
            gl2lds16(kb_bh + ((size_t)(kt * 128 + k)) * DHc + (((tid & 7) ^ (k & 7)) << 3),
                     Ks + p * 2048 + tid * 8);
        }
        // stage Vt tile: same scheme (chunk ^ (d&7) within 128-wide row)
        #pragma unroll
        for (int p = 0; p < 4; p++) {
            int d = p * 16 + (tid >> 4);
            gl2lds16(vt_bh + (size_t)d * Sc + kt * 128 + (((tid & 15) ^ (d & 7)) << 3),
                     Vts + p * 2048 + tid * 8);
        }
        __syncthreads();   // drains vmcnt -> staged data visible

        // ---- QK^T: S[2][8] tiles (32 q-rows x 128 k-cols per wave) ----
        f32x4 sacc[2][8];
        #pragma unroll
        for (int i = 0; i < 2; i++)
            #pragma unroll
            for (int j = 0; j < 8; j++) sacc[i][j] = (f32x4){0.f, 0.f, 0.f, 0.f};
        #pragma unroll
        for (int j = 0; j < 8; j++) {
            const __hip_bfloat16* kp = Ks + (j * 16 + l16) * DHc;   // k&7 == sz
            short8 bk0 = *(const short8*)(kp + ((quad ^ sz) << 3));
            short8 bk1 = *(const short8*)(kp + (((4 + quad) ^ sz) << 3));
            #pragma unroll
            for (int i = 0; i < 2; i++) {
                sacc[i][j] = __builtin_amdgcn_mfma_f32_16x16x32_bf16(afq[i][0], bk0, sacc[i][j], 0, 0, 0);
                sacc[i][j] = __builtin_amdgcn_mfma_f32_16x16x32_bf16(afq[i][1], bk1, sacc[i][j], 0, 0, 0);
            }
        }

        // ---- online softmax (rows live in D-layout: row=quad*4+r, col=j*16+l16) ----
        const bool diag = (kt == qt);
        #pragma unroll
        for (int i = 0; i < 2; i++) {
            #pragma unroll
            for (int r = 0; r < 4; r++) {
                int rowq = w * 32 + i * 16 + quad * 4 + r;
                float rm = -1e30f;
                #pragma unroll
                for (int j = 0; j < 8; j++) {
                    float v = sacc[i][j][r];
                    if (diag && (j * 16 + l16 > rowq)) v = -1e30f;
                    sacc[i][j][r] = v;
                    rm = fmaxf(rm, v);
                }
                #pragma unroll
                for (int dlt = 1; dlt < 16; dlt <<= 1)
                    rm = fmaxf(rm, __shfl_xor(rm, dlt, 64));
                float mn = fmaxf(m[i][r], rm);
                float fm = __expf(m[i][r] - mn);
                m[i][r] = mn;
                float rs = 0.f;
                #pragma unroll
                for (int j = 0; j < 8; j++) {
                    float pe = __expf(sacc[i][j][r] - mn);
                    sacc[i][j][r] = pe;
                    rs += pe;
                }
                #pragma unroll
                for (int dlt = 1; dlt < 16; dlt <<= 1)
                    rs += __shfl_xor(rs, dlt, 64);
                lsum[i][r] = lsum[i][r] * fm + rs;
                #pragma unroll
                for (int dt = 0; dt < 4; dt++) oacc[i][dt][r] *= fm;
            }
        }

        // ---- P -> LDS (wave-private rows; swizzled col ^ ((row&7)<<3)) ----
        #pragma unroll
        for (int i = 0; i < 2; i++) {
            #pragma unroll
            for (int r = 0; r < 4; r++) {
                int Q = w * 32 + i * 16 + quad * 4 + r;
                int rowoff = Q * 128;
                int swz = (Q & 7) << 3;
                #pragma unroll
                for (int j = 0; j < 8; j++)
                    Ps[rowoff + ((j * 16 + l16) ^ swz)] = __float2bfloat16(sacc[i][j][r]);
            }
        }

        // ---- PV: O += P @ V (A from Ps, B from Vts) ----
        #pragma unroll
        for (int kc = 0; kc < 4; kc++) {
            int ch = ((kc * 4 + quad) ^ sz) << 3;
            short8 ap[2], bv[4];
            #pragma unroll
            for (int i = 0; i < 2; i++)
                ap[i] = *(const short8*)(Ps + (w * 32 + i * 16 + l16) * 128 + ch);
            #pragma unroll
            for (int dt = 0; dt < 4; dt++)
                bv[dt] = *(const short8*)(Vts + (dt * 16 + l16) * 128 + ch);
            #pragma unroll
            for (int i = 0; i < 2; i++)
                #pragma unroll
                for (int dt = 0; dt < 4; dt++)
                    oacc[i][dt] = __builtin_amdgcn_mfma_f32_16x16x32_bf16(ap[i], bv[dt], oacc[i][dt], 0, 0, 0);
        }
    }

    // ---- epilogue: divide by l, write bf16 O in [B][S][D] ----
    #pragma unroll
    for (int i = 0; i < 2; i++) {
        #pragma unroll
        for (int r = 0; r < 4; r++) {
            float inv = 1.0f / lsum[i][r];
            int s = qt * 128 + w * 32 + i * 16 + quad * 4 + r;
            size_t base = ((size_t)b * Sc + s) * Dc + h * DHc;
            #pragma unroll
            for (int dt = 0; dt < 4; dt++)
                ob[base + dt * 16 + l16] = __float2bfloat16(oacc[i][dt][r] * inv);
        }
    }
}

__global__ __launch_bounds__(256) void loss_kernel(const float* __restrict__ nll,
                                                   float* __restrict__ out) {
    __shared__ float red[256];
    int tid = threadIdx.x;
    float s = 0.f;
    for (int i = tid; i < Mr; i += 256) s += nll[i];
    red[tid] = s; __syncthreads();
    for (int off = 128; off > 0; off >>= 1) {
        if (tid < off) red[tid] += red[tid + off];
        __syncthreads();
    }
    if (tid == 0) out[0] = red[0] * (1.0f / Mr);
}

// ---------------------------------------------------------------------------
// Host launch
// ---------------------------------------------------------------------------
extern "C" void kernel_launch(void* const* d_in, const int* in_sizes, int n_in,
                              void* d_out, int out_size, void* d_ws, size_t ws_size,
                              hipStream_t stream) {
    const int*   tokens   = (const int*)  d_in[0];
    const int*   targets  = (const int*)  d_in[1];
    const float* word_emb = (const float*)d_in[2];
    const float* pos_emb  = (const float*)d_in[3];
    const float* ln1_w    = (const float*)d_in[4];
    const float* ln1_b    = (const float*)d_in[5];
    const float* wq       = (const float*)d_in[6];
    const float* bq       = (const float*)d_in[7];
    const float* wk       = (const float*)d_in[8];
    const float* bk       = (const float*)d_in[9];
    const float* wv       = (const float*)d_in[10];
    const float* bv       = (const float*)d_in[11];
    const float* wo       = (const float*)d_in[12];
    const float* bo       = (const float*)d_in[13];
    const float* ln2_w    = (const float*)d_in[14];
    const float* ln2_b    = (const float*)d_in[15];
    const float* w1       = (const float*)d_in[16];
    const float* b1       = (const float*)d_in[17];
    const float* w2       = (const float*)d_in[18];
    const float* b2       = (const float*)d_in[19];
    const float* post_w   = (const float*)d_in[20];
    const float* post_b   = (const float*)d_in[21];
    const float* lnf_w    = (const float*)d_in[22];
    const float* lnf_b    = (const float*)d_in[23];
    const float* head_w   = (const float*)d_in[24];

    // Workspace layout (~244 MB)
    float* cur = (float*)d_ws;
    float* x    = cur; cur += (size_t)Mr * Dc;        // 16 MB
    float* nll  = cur; cur += Mr;
    float* tlog = cur; cur += Mr;
    float* bqkv = cur; cur += QKVN;
    float* pmax = cur; cur += (size_t)NVT * Mr;       // 6.4 MB
    float* psum = cur; cur += (size_t)NVT * Mr;       // 6.4 MB
    __hip_bfloat16* bcur = (__hip_bfloat16*)cur;
    __hip_bfloat16* hb     = bcur; bcur += (size_t)Mr * Dc;     // 8 MB
    __hip_bfloat16* ob     = bcur; bcur += (size_t)Mr * Dc;     // 8 MB
    __hip_bfloat16* midb   = bcur; bcur += (size_t)Mr * Fc;     // 32 MB
    __hip_bfloat16* qkvb   = bcur; bcur += (size_t)Mr * QKVN;   // 24 MB
    __hip_bfloat16* qb     = bcur; bcur += (size_t)Mr * Dc;     // 8 MB
    __hip_bfloat16* kbuf   = bcur; bcur += (size_t)Mr * Dc;     // 8 MB
    __hip_bfloat16* Wqkv_t = bcur; bcur += (size_t)QKVN * Dc;   // 6 MB
    __hip_bfloat16* Wo_t   = bcur; bcur += (size_t)Dc * Dc;     // 2 MB
    __hip_bfloat16* W1_t   = bcur; bcur += (size_t)Fc * Dc;     // 8 MB
    __hip_bfloat16* W2_t   = bcur; bcur += (size_t)Dc * Fc;     // 8 MB
    __hip_bfloat16* Wh_t   = bcur; bcur += (size_t)Vpad * Dc;   // 103 MB
    // vtb aliases midb: vtb live only between vt_kernel and attn; midb only in MLP
    __hip_bfloat16* vtb = midb;

    dim3 blk(256);

    embed_kernel<<<Mr, blk, 0, stream>>>(tokens, word_emb, pos_emb, x);
    // head weight convert (once)
    convw_kernel<<<dim3(Vpad / 32, Dc / 32), blk, 0, stream>>>(head_w, Wh_t, Dc, Vc);

    for (int l = 0; l < Lc; l++) {
        // fused QKV weight: rows [0,1024)=wq^T, [1024,2048)=wk^T, [2048,3072)=wv^T
        convw_kernel<<<dim3(Dc / 32, Dc / 32), blk, 0, stream>>>(wq + (size_t)l * Dc * Dc, Wqkv_t, Dc, Dc);
        convw_kernel<<<dim3(Dc / 32, Dc / 32), blk, 0, stream>>>(wk + (size_t)l * Dc * Dc, Wqkv_t + (size_t)Dc * Dc, Dc, Dc);
        convw_kernel<<<dim3(Dc / 32, Dc / 32), blk, 0, stream>>>(wv + (size_t)l * Dc * Dc, Wqkv_t + (size_t)2 * Dc * Dc, Dc, Dc);
        bcat_kernel<<<QKVN / 256, blk, 0, stream>>>(bq + l * Dc, bk + l * Dc, bv + l * Dc, bqkv);

        ln_kernel<<<Mr, blk, 0, stream>>>(x, ln1_w + l * Dc, ln1_b + l * Dc, nullptr, hb);
        bgemm_kernel<<<dim3(QKVN / 128, Mr / 128), blk, 0, stream>>>(
            hb, Wqkv_t, bqkv, nullptr, nullptr, qkvb, QKVN, Dc, 0);
        ropecvt_kernel<<<(Mr * Hc * 32) / 256, blk, 0, stream>>>(qkvb, qb, kbuf);
        vt_kernel<<<dim3(Sc / 32, DHc / 32, Bc * Hc), blk, 0, stream>>>(qkvb, vtb);
        attn_mfma_kernel<<<Bc * Hc * NQT, blk, 0, stream>>>(qb, kbuf, vtb, ob);

        convw_kernel<<<dim3(Dc / 32, Dc / 32), blk, 0, stream>>>(wo + (size_t)l * Dc * Dc, Wo_t, Dc, Dc);
        bgemm_kernel<<<dim3(Dc / 128, Mr / 128), blk, 0, stream>>>(
            ob, Wo_t, bo + l * Dc, x, x, nullptr, Dc, Dc, 0);

        ln_kernel<<<Mr, blk, 0, stream>>>(x, ln2_w + l * Dc, ln2_b + l * Dc, nullptr, hb);
        convw_kernel<<<dim3(Fc / 32, Dc / 32), blk, 0, stream>>>(w1 + (size_t)l * Dc * Fc, W1_t, Dc, Fc);
        bgemm_kernel<<<dim3(Fc / 128, Mr / 128), blk, 0, stream>>>(
            hb, W1_t, b1 + l * Fc, nullptr, nullptr, midb, Fc, Dc, 1);
        convw_kernel<<<dim3(Dc / 32, Fc / 32), blk, 0, stream>>>(w2 + (size_t)l * Fc * Dc, W2_t, Fc, Dc);
        bgemm_kernel<<<dim3(Dc / 128, Mr / 128), blk, 0, stream>>>(
            midb, W2_t, b2 + l * Dc, x, x, nullptr, Dc, Fc, 0);

        if (l == Lc - 1)
            ln_kernel<<<Mr, blk, 0, stream>>>(x, post_w, post_b, x, nullptr);
    }

    ln_kernel<<<Mr, blk, 0, stream>>>(x, lnf_w, lnf_b, nullptr, hb);
    headgemm_kernel<<<dim3(NVT, Mr / 128), blk, 0, stream>>>(hb, Wh_t, targets, pmax, psum, tlog);
    head_reduce_kernel<<<Mr, blk, 0, stream>>>(pmax, psum, tlog, nll);
    loss_kernel<<<1, blk, 0, stream>>>(nll, (float*)d_out);
}

// Round 3
// 2973.857 us; speedup vs baseline: 1.0524x; 1.0524x over previous
//
#include <hip/hip_runtime.h>
#include <hip/hip_bf16.h>
#include <math.h>
#include <stdint.h>

// Problem constants
constexpr int Lc  = 4;
constexpr int Bc  = 2;
constexpr int Sc  = 2048;
constexpr int Dc  = 1024;
constexpr int Hc  = 16;
constexpr int Vc  = 50257;
constexpr int Fc  = 4096;
constexpr int DHc = 64;
constexpr int Mr  = Bc * Sc;       // 4096 token rows
constexpr int QKVN = 3 * Dc;       // 3072 fused QKV width
constexpr int Vpad = 50304;        // vocab padded to 128*393
constexpr int NVT  = Vpad / 128;   // 393 vocab tiles
constexpr int NQT  = Sc / 128;     // 16 q-tiles per (b,h)
constexpr int NSuperH = (NVT + 7) / 8;  // 50 supertiles for head gemm

typedef __attribute__((ext_vector_type(8))) short short8;   // 8 bf16 (4 VGPRs)
typedef __attribute__((ext_vector_type(4))) float f32x4;

// async global->LDS, 16 B per lane; LDS dest must be wave-uniform base + lane*16
__device__ __forceinline__ void gl2lds16(const __hip_bfloat16* g, __hip_bfloat16* l) {
    __builtin_amdgcn_global_load_lds(
        (const uint32_t __attribute__((address_space(1)))*)g,
        (uint32_t __attribute__((address_space(3)))*)l, 16, 0, 0);
}

__device__ __forceinline__ void lse_combine(float& m, float& s, float mo, float so) {
    float mn = fmaxf(m, mo);
    s = s * __expf(m - mn) + so * __expf(mo - mn);
    m = mn;
}

// erf-based exact-GELU via Abramowitz-Stegun 7.1.26 (|err| <= 1.5e-7, far
// below bf16 ulp). Avoids libm erff's branchy slow path in the epilogue.
__device__ __forceinline__ float fast_gelu(float v) {
    float x  = v * 0.70710678118654752f;
    float ax = fabsf(x);
    float t  = 1.0f / (1.0f + 0.3275911f * ax);
    float y  = t * (0.254829592f + t * (-0.284496736f + t * (1.421413741f +
               t * (-1.453152027f + t * 1.061405429f))));
    float erfv = 1.0f - y * __expf(-ax * ax);
    erfv = (x < 0.f) ? -erfv : erfv;
    return 0.5f * v * (1.0f + erfv);
}

// ---------------------------------------------------------------------------
// Embedding
// ---------------------------------------------------------------------------
__global__ void embed_kernel(const int* __restrict__ tokens,
                             const float* __restrict__ we,
                             const float* __restrict__ pe,
                             float* __restrict__ x) {
    int row = blockIdx.x;
    int s   = row & (Sc - 1);
    int tok = tokens[row];
    const float* wp = we + (size_t)tok * Dc;
    const float* pp = pe + (size_t)s * Dc;
    float* xp = x + (size_t)row * Dc;
    for (int i = threadIdx.x; i < Dc; i += blockDim.x)
        xp[i] = wp[i] + pp[i];
}

// ---------------------------------------------------------------------------
// LayerNorm; optional fp32 and/or bf16 outputs. Safe in-place for outF==x.
// ---------------------------------------------------------------------------
__global__ __launch_bounds__(256) void ln_kernel(const float* __restrict__ x,
                                                 const float* __restrict__ w,
                                                 const float* __restrict__ b,
                                                 float* __restrict__ outF,
                                                 __hip_bfloat16* __restrict__ outB) {
    __shared__ float red[256];
    int row = blockIdx.x;
    int tid = threadIdx.x;
    const float* xp = x + (size_t)row * Dc;
    float s1 = 0.f, s2 = 0.f;
    for (int i = tid; i < Dc; i += 256) {
        float v = xp[i];
        s1 += v; s2 += v * v;
    }
    red[tid] = s1; __syncthreads();
    for (int off = 128; off > 0; off >>= 1) {
        if (tid < off) red[tid] += red[tid + off];
        __syncthreads();
    }
    float mean = red[0] * (1.0f / Dc);
    __syncthreads();
    red[tid] = s2; __syncthreads();
    for (int off = 128; off > 0; off >>= 1) {
        if (tid < off) red[tid] += red[tid + off];
        __syncthreads();
    }
    float var  = red[0] * (1.0f / Dc) - mean * mean;
    float rstd = rsqrtf(var + 1e-5f);
    for (int i = tid; i < Dc; i += 256) {
        float v = (xp[i] - mean) * rstd * w[i] + b[i];
        if (outF) outF[(size_t)row * Dc + i] = v;
        if (outB) outB[(size_t)row * Dc + i] = __float2bfloat16(v);
    }
}

// ---------------------------------------------------------------------------
// Weight transpose + bf16 convert: W [K][srcN] f32 -> Wt [dstN][K] bf16,
// rows >= srcN zero-filled. Grid (dstN/32, K/32), block 256.
// ---------------------------------------------------------------------------
__global__ __launch_bounds__(256) void convw_kernel(const float* __restrict__ W,
                                                    __hip_bfloat16* __restrict__ Wt,
                                                    int K, int srcN) {
    __shared__ float t[32][33];
    int n0 = blockIdx.x * 32, k0 = blockIdx.y * 32;
    int tx = threadIdx.x & 31, ty = threadIdx.x >> 5;
    #pragma unroll
    for (int j = 0; j < 4; j++) {
        int k = k0 + ty + j * 8, n = n0 + tx;
        t[ty + j * 8][tx] = (n < srcN) ? W[(size_t)k * srcN + n] : 0.f;
    }
    __syncthreads();
    #pragma unroll
    for (int j = 0; j < 4; j++) {
        int n = n0 + ty + j * 8, k = k0 + tx;
        Wt[(size_t)n * K + k] = __float2bfloat16(t[tx][ty + j * 8]);
    }
}

__global__ void bcat_kernel(const float* __restrict__ bq, const float* __restrict__ bk,
                            const float* __restrict__ bv, float* __restrict__ o) {
    int i = blockIdx.x * 256 + threadIdx.x;
    if (i < QKVN)
        o[i] = (i < Dc) ? bq[i] : (i < 2 * Dc) ? bk[i - Dc] : bv[i - 2 * Dc];
}

// ---------------------------------------------------------------------------
// bf16 MFMA GEMM (m97 structure): C = act(A @ Bt^T + bias [+ Cin]).
// A [M][K] bf16, Bt [N][K] bf16 (i.e. B transposed). Tile 128x128, BK=32.
// 1-D grid, supertile-linearized: 256-block supertiles = 8 col-tiles x all
// 32 row-tiles, so a resident XCD's working set is ~4 A-panels + 8 B-panels
// (~3 MB < 4 MB L2) instead of streaming 64 different B-panels.
// Grid = (N/1024)*256 blocks. M == Mr (4096), N mult of 1024, K mult of 32.
// ---------------------------------------------------------------------------
__global__ __launch_bounds__(256) void bgemm_kernel(
    const __hip_bfloat16* __restrict__ A,
    const __hip_bfloat16* __restrict__ Bt,
    const float* __restrict__ bias,
    const float* __restrict__ Cin,
    float* __restrict__ outF,
    __hip_bfloat16* __restrict__ outB,
    int N, int K, int act) {
    __shared__ __align__(16) __hip_bfloat16 As[128 * 32];
    __shared__ __align__(16) __hip_bfloat16 Bs[128 * 32];
    const int tid = threadIdx.x;
    const int bid = blockIdx.x;
    const int sup = bid >> 8, wblk = bid & 255;
    const int rowBase = (wblk & 31) * 128;
    const int colBase = (sup * 8 + (wblk >> 5)) * 128;
    const int w = tid >> 6, lane = tid & 63;
    const int wm = w >> 1, wn = w & 1;
    const int quad = lane >> 4, l16 = lane & 15;

    f32x4 acc[4][4];
    #pragma unroll
    for (int i = 0; i < 4; i++)
        #pragma unroll
        for (int j = 0; j < 4; j++) acc[i][j] = (f32x4){0.f, 0.f, 0.f, 0.f};

    const __hip_bfloat16* a0 = A  + (size_t)(rowBase + (tid >> 2)) * K + (tid & 3) * 8;
    const __hip_bfloat16* b0 = Bt + (size_t)(colBase + (tid >> 2)) * K + (tid & 3) * 8;
    const size_t rstep = (size_t)64 * K;
    __hip_bfloat16* lA = As + tid * 8;
    __hip_bfloat16* lB = Bs + tid * 8;

    for (int k0 = 0; k0 < K; k0 += 32) {
        __syncthreads();
        gl2lds16(a0 + k0,         lA);
        gl2lds16(a0 + k0 + rstep, lA + 2048);
        gl2lds16(b0 + k0,         lB);
        gl2lds16(b0 + k0 + rstep, lB + 2048);
        __syncthreads();

        short8 af[4], bf[4];
        #pragma unroll
        for (int i = 0; i < 4; i++) {
            af[i] = *(const short8*)(As + (wm * 64 + i * 16 + l16) * 32 + quad * 8);
            bf[i] = *(const short8*)(Bs + (wn * 64 + i * 16 + l16) * 32 + quad * 8);
        }
        #pragma unroll
        for (int i = 0; i < 4; i++)
            #pragma unroll
            for (int j = 0; j < 4; j++)
                acc[i][j] = __builtin_amdgcn_mfma_f32_16x16x32_bf16(af[i], bf[j], acc[i][j], 0, 0, 0);
    }

    #pragma unroll
    for (int i = 0; i < 4; i++) {
        #pragma unroll
        for (int j = 0; j < 4; j++) {
            int col = colBase + wn * 64 + j * 16 + l16;
            float bb = bias ? bias[col] : 0.f;
            #pragma unroll
            for (int r = 0; r < 4; r++) {
                int row = rowBase + wm * 64 + i * 16 + quad * 4 + r;
                float v = acc[i][j][r] + bb;
                if (Cin) v += Cin[(size_t)row * N + col];
                if (act) v = fast_gelu(v);
                if (outF) outF[(size_t)row * N + col] = v;
                if (outB) outB[(size_t)row * N + col] = __float2bfloat16(v);
            }
        }
    }
}

// ---------------------------------------------------------------------------
// Head GEMM (same core) with fused per-row partial logsumexp over the block's
// 128 vocab cols + target-logit capture. Logits never hit global memory.
// 1-D supertile grid (NSuperH*256 blocks); epilogue restructured: cheap
// max-butterfly (fmax+shfl only), one local __expf pass, add-butterfly.
// Partials: pmax/psum [NVT][Mr].
// ---------------------------------------------------------------------------
__global__ __launch_bounds__(256) void headgemm_kernel(
    const __hip_bfloat16* __restrict__ A,
    const __hip_bfloat16* __restrict__ Bt,
    const int* __restrict__ targets,
    float* __restrict__ pmax, float* __restrict__ psum,
    float* __restrict__ tlog) {
    __shared__ __align__(16) __hip_bfloat16 As[128 * 32];
    __shared__ __align__(16) __hip_bfloat16 Bs[128 * 32];
    __shared__ float pmW[2][128], psW[2][128];
    __shared__ int tg[128];
    const int tid = threadIdx.x;
    const int bid = blockIdx.x;
    const int sup = bid >> 8, wblk = bid & 255;
    const int rowBase = (wblk & 31) * 128;
    const int colT = sup * 8 + (wblk >> 5);
    if (colT >= NVT) return;                 // supertile padding (uniform exit)
    const int colBase = colT * 128;
    const int K = Dc;
    const int w = tid >> 6, lane = tid & 63;
    const int wm = w >> 1, wn = w & 1;
    const int quad = lane >> 4, l16 = lane & 15;

    if (tid < 128) tg[tid] = targets[rowBase + tid];

    f32x4 acc[4][4];
    #pragma unroll
    for (int i = 0; i < 4; i++)
        #pragma unroll
        for (int j = 0; j < 4; j++) acc[i][j] = (f32x4){0.f, 0.f, 0.f, 0.f};

    const __hip_bfloat16* a0 = A  + (size_t)(rowBase + (tid >> 2)) * K + (tid & 3) * 8;
    const __hip_bfloat16* b0 = Bt + (size_t)(colBase + (tid >> 2)) * K + (tid & 3) * 8;
    const size_t rstep = (size_t)64 * K;
    __hip_bfloat16* lA = As + tid * 8;
    __hip_bfloat16* lB = Bs + tid * 8;

    for (int k0 = 0; k0 < K; k0 += 32) {
        __syncthreads();
        gl2lds16(a0 + k0,         lA);
        gl2lds16(a0 + k0 + rstep, lA + 2048);
        gl2lds16(b0 + k0,         lB);
        gl2lds16(b0 + k0 + rstep, lB + 2048);
        __syncthreads();

        short8 af[4], bf[4];
        #pragma unroll
        for (int i = 0; i < 4; i++) {
            af[i] = *(const short8*)(As + (wm * 64 + i * 16 + l16) * 32 + quad * 8);
            bf[i] = *(const short8*)(Bs + (wn * 64 + i * 16 + l16) * 32 + quad * 8);
        }
        #pragma unroll
        for (int i = 0; i < 4; i++)
            #pragma unroll
            for (int j = 0; j < 4; j++)
                acc[i][j] = __builtin_amdgcn_mfma_f32_16x16x32_bf16(af[i], bf[j], acc[i][j], 0, 0, 0);
    }

    #pragma unroll
    for (int i = 0; i < 4; i++) {
        #pragma unroll
        for (int r = 0; r < 4; r++) {
            int rib = wm * 64 + i * 16 + quad * 4 + r;
            int tgt = tg[rib];
            float vals[4];
            float m = -1e30f;
            #pragma unroll
            for (int j = 0; j < 4; j++) {
                int col = colBase + wn * 64 + j * 16 + l16;
                float v = acc[i][j][r];
                bool ok = (col < Vc);
                if (ok && col == tgt) tlog[rowBase + rib] = v;
                vals[j] = ok ? v : -1e30f;
                m = fmaxf(m, vals[j]);
            }
            // cheap max butterfly across the 16 l16 lanes
            #pragma unroll
            for (int d = 1; d < 16; d <<= 1)
                m = fmaxf(m, __shfl_xor(m, d, 64));
            // single local exp pass (masked cols underflow to 0)
            float s = 0.f;
            #pragma unroll
            for (int j = 0; j < 4; j++) s += __expf(vals[j] - m);
            #pragma unroll
            for (int d = 1; d < 16; d <<= 1)
                s += __shfl_xor(s, d, 64);
            if (l16 == 0) { pmW[wn][rib] = m; psW[wn][rib] = s; }
        }
    }
    __syncthreads();
    if (tid < 128) {
        float m = pmW[0][tid], s = psW[0][tid];
        lse_combine(m, s, pmW[1][tid], psW[1][tid]);
        pmax[(size_t)colT * Mr + rowBase + tid] = m;
        psum[(size_t)colT * Mr + rowBase + tid] = s;
    }
}

__global__ __launch_bounds__(256) void head_reduce_kernel(
    const float* __restrict__ pmax, const float* __restrict__ psum,
    const float* __restrict__ tlog, float* __restrict__ nll) {
    __shared__ float rm[256], rs[256];
    int row = blockIdx.x;
    int tid = threadIdx.x;
    float m = -1e30f, s = 0.f;
    for (int t = tid; t < NVT; t += 256)
        lse_combine(m, s, pmax[(size_t)t * Mr + row], psum[(size_t)t * Mr + row]);
    rm[tid] = m; rs[tid] = s; __syncthreads();
    for (int off = 128; off > 0; off >>= 1) {
        if (tid < off) {
            float mm = rm[tid], ss = rs[tid];
            lse_combine(mm, ss, rm[tid + off], rs[tid + off]);
            rm[tid] = mm; rs[tid] = ss;
        }
        __syncthreads();
    }
    if (tid == 0) nll[row] = rm[0] + logf(rs[0]) - tlog[row];
}

// ---------------------------------------------------------------------------
// RoPE + bf16 split: reads fused bf16 qkv [Mr][3072]; writes
// qb [B*H][S][64] (pre-scaled by 1/sqrt(DH)) and kb [B*H][S][64].
// ---------------------------------------------------------------------------
__global__ void ropecvt_kernel(const __hip_bfloat16* __restrict__ qkvb,
                               __hip_bfloat16* __restrict__ qb,
                               __hip_bfloat16* __restrict__ kb) {
    int p = blockIdx.x * blockDim.x + threadIdx.x;
    if (p >= Mr * Hc * 32) return;
    int j    = p & 31;
    int h    = (p >> 5) & (Hc - 1);
    int srow = p >> 9;
    int s    = srow & (Sc - 1);
    int b    = srow >> 11;
    float inv = powf(10000.0f, -(float)(2 * j) * (1.0f / 64.0f));
    float fr  = (float)s * inv;
    float c = cosf(fr), sn = sinf(fr);
    size_t base = (size_t)srow * QKVN + h * DHc;
    size_t o = ((size_t)(b * Hc + h) * Sc + s) * DHc;
    float q1 = __bfloat162float(qkvb[base + j]);
    float q2 = __bfloat162float(qkvb[base + j + 32]);
    qb[o + j]      = __float2bfloat16((q1 * c - q2 * sn) * 0.125f);
    qb[o + j + 32] = __float2bfloat16((q2 * c + q1 * sn) * 0.125f);
    float k1 = __bfloat162float(qkvb[base + Dc + j]);
    float k2 = __bfloat162float(qkvb[base + Dc + j + 32]);
    kb[o + j]      = __float2bfloat16(k1 * c - k2 * sn);
    kb[o + j + 32] = __float2bfloat16(k2 * c + k1 * sn);
}

// ---------------------------------------------------------------------------
// V transpose: fused qkv [Mr][3072] bf16 -> vtb [B*H][64][S] bf16.
// Grid (S/32, DH/32, B*H), block 256, LDS-tiled.
// ---------------------------------------------------------------------------
__global__ __launch_bounds__(256) void vt_kernel(const __hip_bfloat16* __restrict__ qkvb,
                                                 __hip_bfloat16* __restrict__ vtb) {
    __shared__ float t[32][33];
    int s0 = blockIdx.x * 32, d0 = blockIdx.y * 32;
    int bh = blockIdx.z;
    int b = bh >> 4, h = bh & (Hc - 1);
    int tx = threadIdx.x & 31, ty = threadIdx.x >> 5;
    #pragma unroll
    for (int jj = 0; jj < 4; jj++) {
        int s = s0 + ty + jj * 8;
        t[ty + jj * 8][tx] = __bfloat162float(
            qkvb[((size_t)(b * Sc + s)) * QKVN + 2 * Dc + h * DHc + d0 + tx]);
    }
    __syncthreads();
    #pragma unroll
    for (int jj = 0; jj < 4; jj++) {
        int d = d0 + ty + jj * 8;
        vtb[((size_t)bh * DHc + d) * Sc + s0 + tx] = __float2bfloat16(t[tx][ty + jj * 8]);
    }
}

// ---------------------------------------------------------------------------
// Flash attention, MFMA. One block per (b,h,qtile): 512 blocks, 4 waves.
// Wave w owns q-rows [w*32, w*32+32); full 128-col K tile per wave so the
// online softmax reduces purely intra-wave (shfl over l16 bits).
// K tile [128][64] and Vt tile [64][128] staged via global_load_lds with
// pre-swizzled global source (chunk ^= row&7) so swizzled ds_read_b128 is
// bank-conflict-free (G4/T2). P round-trips through wave-private swizzled
// LDS rows to convert D-frag layout -> A-frag layout.
// ---------------------------------------------------------------------------
__global__ __launch_bounds__(256) void attn_mfma_kernel(
    const __hip_bfloat16* __restrict__ qb,
    const __hip_bfloat16* __restrict__ kb,
    const __hip_bfloat16* __restrict__ vtb,
    __hip_bfloat16* __restrict__ ob) {
    __shared__ __align__(16) __hip_bfloat16 Ks[128 * 64];    // 16 KB
    __shared__ __align__(16) __hip_bfloat16 Vts[64 * 128];   // 16 KB
    __shared__ __align__(16) __hip_bfloat16 Ps[128 * 128];   // 32 KB

    const int tid  = threadIdx.x;
    const int idx  = blockIdx.x;
    const int qt   = (NQT - 1) - (idx >> 5);   // heavy q-tiles dispatch first (LPT)
    const int bh   = idx & 31;
    const int b    = bh >> 4, h = bh & (Hc - 1);
    const int w    = tid >> 6, lane = tid & 63;
    const int quad = lane >> 4, l16 = lane & 15;
    const int sz   = l16 & 7;                  // row&7 swizzle term for l16-mapped rows

    const __hip_bfloat16* kb_bh = kb  + (size_t)bh * Sc * DHc;
    const __hip_bfloat16* vt_bh = vtb + (size_t)bh * DHc * Sc;

    // Q fragments held in registers for the whole block (A-frag: row=l16, k=quad*8+j)
    short8 afq[2][2];
    {
        const __hip_bfloat16* qp =
            qb + ((size_t)bh * Sc + qt * 128 + w * 32 + l16) * DHc;
        #pragma unroll
        for (int i = 0; i < 2; i++)
            #pragma unroll
            for (int dc = 0; dc < 2; dc++)
                afq[i][dc] = *(const short8*)(qp + i * 16 * DHc + (dc * 4 + quad) * 8);
    }

    f32x4 oacc[2][4];
    float m[2][4], lsum[2][4];
    #pragma unroll
    for (int i = 0; i < 2; i++)
        #pragma unroll
        for (int dt = 0; dt < 4; dt++) oacc[i][dt] = (f32x4){0.f, 0.f, 0.f, 0.f};
    #pragma unroll
    for (int i = 0; i < 2; i++)
        #pragma unroll
        for (int r = 0; r < 4; r++) { m[i][r] = -1e30f; lsum[i][r] = 0.f; }

    for (int kt = 0; kt <= qt; ++kt) {
        __syncthreads();   // all waves done reading Ks/Vts of previous tile
        // stage K tile: LDS linear, global source pre-swizzled (chunk ^ (k&7))
        #pragma unroll
        for (int p = 0; p < 4; p++) {
            int k = p * 32 + (tid >> 3);
            gl2lds16(kb_bh + ((size_t)(kt * 128 + k)) * DHc + (((tid & 7) ^ (k & 7)) << 3),
                     Ks + p * 2048 + tid * 8);
        }
        // stage Vt tile: same scheme (chunk ^ (d&7) within 128-wide row)
        #pragma unroll
        for (int p = 0; p < 4; p++) {
            int d = p * 16 + (tid >> 4);
            gl2lds16(vt_bh + (size_t)d * Sc + kt * 128 + (((tid & 15) ^ (d & 7)) << 3),
                     Vts + p * 2048 + tid * 8);
        }
        __syncthreads();   // drains vmcnt -> staged data visible

        // ---- QK^T: S[2][8] tiles (32 q-rows x 128 k-cols per wave) ----
        f32x4 sacc[2][8];
        #pragma unroll
        for (int i = 0; i < 2; i++)
            #pragma unroll
            for (int j = 0; j < 8; j++) sacc[i][j] = (f32x4){0.f, 0.f, 0.f, 0.f};
        #pragma unroll
        for (int j = 0; j < 8; j++) {
            const __hip_bfloat16* kp = Ks + (j * 16 + l16) * DHc;   // k&7 == sz
            short8 bk0 = *(const short8*)(kp + ((quad ^ sz) << 3));
            short8 bk1 = *(const short8*)(kp + (((4 + quad) ^ sz) << 3));
            #pragma unroll
            for (int i = 0; i < 2; i++) {
                sacc[i][j] = __builtin_amdgcn_mfma_f32_16x16x32_bf16(afq[i][0], bk0, sacc[i][j], 0, 0, 0);
                sacc[i][j] = __builtin_amdgcn_mfma_f32_16x16x32_bf16(afq[i][1], bk1, sacc[i][j], 0, 0, 0);
            }
        }

        // ---- online softmax (rows live in D-layout: row=quad*4+r, col=j*16+l16) ----
        const bool diag = (kt == qt);
        #pragma unroll
        for (int i = 0; i < 2; i++) {
            #pragma unroll
            for (int r = 0; r < 4; r++) {
                int rowq = w * 32 + i * 16 + quad * 4 + r;
                float rm = -1e30f;
                #pragma unroll
                for (int j = 0; j < 8; j++) {
                    float v = sacc[i][j][r];
                    if (diag && (j * 16 + l16 > rowq)) v = -1e30f;
                    sacc[i][j][r] = v;
                    rm = fmaxf(rm, v);
                }
                #pragma unroll
                for (int dlt = 1; dlt < 16; dlt <<= 1)
                    rm = fmaxf(rm, __shfl_xor(rm, dlt, 64));
                float mn = fmaxf(m[i][r], rm);
                float fm = __expf(m[i][r] - mn);
                m[i][r] = mn;
                float rs = 0.f;
                #pragma unroll
                for (int j = 0; j < 8; j++) {
                    float pe = __expf(sacc[i][j][r] - mn);
                    sacc[i][j][r] = pe;
                    rs += pe;
                }
                #pragma unroll
                for (int dlt = 1; dlt < 16; dlt <<= 1)
                    rs += __shfl_xor(rs, dlt, 64);
                lsum[i][r] = lsum[i][r] * fm + rs;
                #pragma unroll
                for (int dt = 0; dt < 4; dt++) oacc[i][dt][r] *= fm;
            }
        }

        // ---- P -> LDS (wave-private rows; swizzled col ^ ((row&7)<<3)) ----
        #pragma unroll
        for (int i = 0; i < 2; i++) {
            #pragma unroll
            for (int r = 0; r < 4; r++) {
                int Q = w * 32 + i * 16 + quad * 4 + r;
                int rowoff = Q * 128;
                int swz = (Q & 7) << 3;
                #pragma unroll
                for (int j = 0; j < 8; j++)
                    Ps[rowoff + ((j * 16 + l16) ^ swz)] = __float2bfloat16(sacc[i][j][r]);
            }
        }

        // ---- PV: O += P @ V (A from Ps, B from Vts) ----
        #pragma unroll
        for (int kc = 0; kc < 4; kc++) {
            int ch = ((kc * 4 + quad) ^ sz) << 3;
            short8 ap[2], bv[4];
            #pragma unroll
            for (int i = 0; i < 2; i++)
                ap[i] = *(const short8*)(Ps + (w * 32 + i * 16 + l16) * 128 + ch);
            #pragma unroll
            for (int dt = 0; dt < 4; dt++)
                bv[dt] = *(const short8*)(Vts + (dt * 16 + l16) * 128 + ch);
            #pragma unroll
            for (int i = 0; i < 2; i++)
                #pragma unroll
                for (int dt = 0; dt < 4; dt++)
                    oacc[i][dt] = __builtin_amdgcn_mfma_f32_16x16x32_bf16(ap[i], bv[dt], oacc[i][dt], 0, 0, 0);
        }
    }

    // ---- epilogue: divide by l, write bf16 O in [B][S][D] ----
    #pragma unroll
    for (int i = 0; i < 2; i++) {
        #pragma unroll
        for (int r = 0; r < 4; r++) {
            float inv = 1.0f / lsum[i][r];
            int s = qt * 128 + w * 32 + i * 16 + quad * 4 + r;
            size_t base = ((size_t)b * Sc + s) * Dc + h * DHc;
            #pragma unroll
            for (int dt = 0; dt < 4; dt++)
                ob[base + dt * 16 + l16] = __float2bfloat16(oacc[i][dt][r] * inv);
        }
    }
}

__global__ __launch_bounds__(256) void loss_kernel(const float* __restrict__ nll,
                                                   float* __restrict__ out) {
    __shared__ float red[256];
    int tid = threadIdx.x;
    float s = 0.f;
    for (int i = tid; i < Mr; i += 256) s += nll[i];
    red[tid] = s; __syncthreads();
    for (int off = 128; off > 0; off >>= 1) {
        if (tid < off) red[tid] += red[tid + off];
        __syncthreads();
    }
    if (tid == 0) out[0] = red[0] * (1.0f / Mr);
}

// ---------------------------------------------------------------------------
// Host launch
// ---------------------------------------------------------------------------
extern "C" void kernel_launch(void* const* d_in, const int* in_sizes, int n_in,
                              void* d_out, int out_size, void* d_ws, size_t ws_size,
                              hipStream_t stream) {
    const int*   tokens   = (const int*)  d_in[0];
    const int*   targets  = (const int*)  d_in[1];
    const float* word_emb = (const float*)d_in[2];
    const float* pos_emb  = (const float*)d_in[3];
    const float* ln1_w    = (const float*)d_in[4];
    const float* ln1_b    = (const float*)d_in[5];
    const float* wq       = (const float*)d_in[6];
    const float* bq       = (const float*)d_in[7];
    const float* wk       = (const float*)d_in[8];
    const float* bk       = (const float*)d_in[9];
    const float* wv       = (const float*)d_in[10];
    const float* bv       = (const float*)d_in[11];
    const float* wo       = (const float*)d_in[12];
    const float* bo       = (const float*)d_in[13];
    const float* ln2_w    = (const float*)d_in[14];
    const float* ln2_b    = (const float*)d_in[15];
    const float* w1       = (const float*)d_in[16];
    const float* b1       = (const float*)d_in[17];
    const float* w2       = (const float*)d_in[18];
    const float* b2       = (const float*)d_in[19];
    const float* post_w   = (const float*)d_in[20];
    const float* post_b   = (const float*)d_in[21];
    const float* lnf_w    = (const float*)d_in[22];
    const float* lnf_b    = (const float*)d_in[23];
    const float* head_w   = (const float*)d_in[24];

    // Workspace layout (~244 MB)
    float* cur = (float*)d_ws;
    float* x    = cur; cur += (size_t)Mr * Dc;        // 16 MB
    float* nll  = cur; cur += Mr;
    float* tlog = cur; cur += Mr;
    float* bqkv = cur; cur += QKVN;
    float* pmax = cur; cur += (size_t)NVT * Mr;       // 6.4 MB
    float* psum = cur; cur += (size_t)NVT * Mr;       // 6.4 MB
    __hip_bfloat16* bcur = (__hip_bfloat16*)cur;
    __hip_bfloat16* hb     = bcur; bcur += (size_t)Mr * Dc;     // 8 MB
    __hip_bfloat16* ob     = bcur; bcur += (size_t)Mr * Dc;     // 8 MB
    __hip_bfloat16* midb   = bcur; bcur += (size_t)Mr * Fc;     // 32 MB
    __hip_bfloat16* qkvb   = bcur; bcur += (size_t)Mr * QKVN;   // 24 MB
    __hip_bfloat16* qb     = bcur; bcur += (size_t)Mr * Dc;     // 8 MB
    __hip_bfloat16* kbuf   = bcur; bcur += (size_t)Mr * Dc;     // 8 MB
    __hip_bfloat16* Wqkv_t = bcur; bcur += (size_t)QKVN * Dc;   // 6 MB
    __hip_bfloat16* Wo_t   = bcur; bcur += (size_t)Dc * Dc;     // 2 MB
    __hip_bfloat16* W1_t   = bcur; bcur += (size_t)Fc * Dc;     // 8 MB
    __hip_bfloat16* W2_t   = bcur; bcur += (size_t)Dc * Fc;     // 8 MB
    __hip_bfloat16* Wh_t   = bcur; bcur += (size_t)Vpad * Dc;   // 103 MB
    // vtb aliases midb: vtb live only between vt_kernel and attn; midb only in MLP
    __hip_bfloat16* vtb = midb;

    dim3 blk(256);

    embed_kernel<<<Mr, blk, 0, stream>>>(tokens, word_emb, pos_emb, x);
    // head weight convert (once)
    convw_kernel<<<dim3(Vpad / 32, Dc / 32), blk, 0, stream>>>(head_w, Wh_t, Dc, Vc);

    for (int l = 0; l < Lc; l++) {
        // fused QKV weight: rows [0,1024)=wq^T, [1024,2048)=wk^T, [2048,3072)=wv^T
        convw_kernel<<<dim3(Dc / 32, Dc / 32), blk, 0, stream>>>(wq + (size_t)l * Dc * Dc, Wqkv_t, Dc, Dc);
        convw_kernel<<<dim3(Dc / 32, Dc / 32), blk, 0, stream>>>(wk + (size_t)l * Dc * Dc, Wqkv_t + (size_t)Dc * Dc, Dc, Dc);
        convw_kernel<<<dim3(Dc / 32, Dc / 32), blk, 0, stream>>>(wv + (size_t)l * Dc * Dc, Wqkv_t + (size_t)2 * Dc * Dc, Dc, Dc);
        bcat_kernel<<<QKVN / 256, blk, 0, stream>>>(bq + l * Dc, bk + l * Dc, bv + l * Dc, bqkv);

        ln_kernel<<<Mr, blk, 0, stream>>>(x, ln1_w + l * Dc, ln1_b + l * Dc, nullptr, hb);
        bgemm_kernel<<<(QKVN / 1024) * 256, blk, 0, stream>>>(
            hb, Wqkv_t, bqkv, nullptr, nullptr, qkvb, QKVN, Dc, 0);
        ropecvt_kernel<<<(Mr * Hc * 32) / 256, blk, 0, stream>>>(qkvb, qb, kbuf);
        vt_kernel<<<dim3(Sc / 32, DHc / 32, Bc * Hc), blk, 0, stream>>>(qkvb, vtb);
        attn_mfma_kernel<<<Bc * Hc * NQT, blk, 0, stream>>>(qb, kbuf, vtb, ob);

        convw_kernel<<<dim3(Dc / 32, Dc / 32), blk, 0, stream>>>(wo + (size_t)l * Dc * Dc, Wo_t, Dc, Dc);
        bgemm_kernel<<<(Dc / 1024) * 256, blk, 0, stream>>>(
            ob, Wo_t, bo + l * Dc, x, x, nullptr, Dc, Dc, 0);

        ln_kernel<<<Mr, blk, 0, stream>>>(x, ln2_w + l * Dc, ln2_b + l * Dc, nullptr, hb);
        convw_kernel<<<dim3(Fc / 32, Dc / 32), blk, 0, stream>>>(w1 + (size_t)l * Dc * Fc, W1_t, Dc, Fc);
        bgemm_kernel<<<(Fc / 1024) * 256, blk, 0, stream>>>(
            hb, W1_t, b1 + l * Fc, nullptr, nullptr, midb, Fc, Dc, 1);
        convw_kernel<<<dim3(Dc / 32, Fc / 32), blk, 0, stream>>>(w2 + (size_t)l * Fc * Dc, W2_t, Fc, Dc);
        bgemm_kernel<<<(Dc / 1024) * 256, blk, 0, stream>>>(
            midb, W2_t, b2 + l * Dc, x, x, nullptr, Dc, Fc, 0);

        if (l == Lc - 1)
            ln_kernel<<<Mr, blk, 0, stream>>>(x, post_w, post_b, x, nullptr);
    }

    ln_kernel<<<Mr, blk, 0, stream>>>(x, lnf_w, lnf_b, nullptr, hb);
    headgemm_kernel<<<NSuperH * 256, blk, 0, stream>>>(hb, Wh_t, targets, pmax, psum, tlog);
    head_reduce_kernel<<<Mr, blk, 0, stream>>>(pmax, psum, tlog, nll);
    loss_kernel<<<1, blk, 0, stream>>>(nll, (float*)d_out);
}

// Round 4
// 2826.686 us; speedup vs baseline: 1.1072x; 1.0521x over previous
//
#include <hip/hip_runtime.h>
#include <hip/hip_bf16.h>
#include <math.h>
#include <stdint.h>

// Problem constants
constexpr int Lc  = 4;
constexpr int Bc  = 2;
constexpr int Sc  = 2048;
constexpr int Dc  = 1024;
constexpr int Hc  = 16;
constexpr int Vc  = 50257;
constexpr int Fc  = 4096;
constexpr int DHc = 64;
constexpr int Mr  = Bc * Sc;       // 4096 token rows
constexpr int QKVN = 3 * Dc;       // 3072 fused QKV width
constexpr int Vpad = 50432;        // vocab padded to 256*197
constexpr int NVT  = Vpad / 256;   // 197 vocab tiles (256-wide)
constexpr int NQT  = Sc / 128;     // 16 q-tiles per (b,h)

typedef __attribute__((ext_vector_type(8))) short short8;   // 8 bf16 (4 VGPRs)
typedef __attribute__((ext_vector_type(4))) float f32x4;

// async global->LDS, 16 B per lane; LDS dest must be wave-uniform base + lane*16
__device__ __forceinline__ void gl2lds16(const __hip_bfloat16* g, __hip_bfloat16* l) {
    __builtin_amdgcn_global_load_lds(
        (const uint32_t __attribute__((address_space(1)))*)g,
        (uint32_t __attribute__((address_space(3)))*)l, 16, 0, 0);
}

__device__ __forceinline__ void lse_combine(float& m, float& s, float mo, float so) {
    float mn = fmaxf(m, mo);
    s = s * __expf(m - mn) + so * __expf(mo - mn);
    m = mn;
}

// erf-based exact-GELU via Abramowitz-Stegun 7.1.26 (|err| <= 1.5e-7, far
// below bf16 ulp). Avoids libm erff's branchy slow path in the epilogue.
__device__ __forceinline__ float fast_gelu(float v) {
    float x  = v * 0.70710678118654752f;
    float ax = fabsf(x);
    float t  = 1.0f / (1.0f + 0.3275911f * ax);
    float y  = t * (0.254829592f + t * (-0.284496736f + t * (1.421413741f +
               t * (-1.453152027f + t * 1.061405429f))));
    float erfv = 1.0f - y * __expf(-ax * ax);
    erfv = (x < 0.f) ? -erfv : erfv;
    return 0.5f * v * (1.0f + erfv);
}

// ---------------------------------------------------------------------------
// Embedding
// ---------------------------------------------------------------------------
__global__ void embed_kernel(const int* __restrict__ tokens,
                             const float* __restrict__ we,
                             const float* __restrict__ pe,
                             float* __restrict__ x) {
    int row = blockIdx.x;
    int s   = row & (Sc - 1);
    int tok = tokens[row];
    const float* wp = we + (size_t)tok * Dc;
    const float* pp = pe + (size_t)s * Dc;
    float* xp = x + (size_t)row * Dc;
    for (int i = threadIdx.x; i < Dc; i += blockDim.x)
        xp[i] = wp[i] + pp[i];
}

// ---------------------------------------------------------------------------
// LayerNorm; optional fp32 and/or bf16 outputs. Safe in-place for outF==x.
// ---------------------------------------------------------------------------
__global__ __launch_bounds__(256) void ln_kernel(const float* __restrict__ x,
                                                 const float* __restrict__ w,
                                                 const float* __restrict__ b,
                                                 float* __restrict__ outF,
                                                 __hip_bfloat16* __restrict__ outB) {
    __shared__ float red[256];
    int row = blockIdx.x;
    int tid = threadIdx.x;
    const float* xp = x + (size_t)row * Dc;
    float s1 = 0.f, s2 = 0.f;
    for (int i = tid; i < Dc; i += 256) {
        float v = xp[i];
        s1 += v; s2 += v * v;
    }
    red[tid] = s1; __syncthreads();
    for (int off = 128; off > 0; off >>= 1) {
        if (tid < off) red[tid] += red[tid + off];
        __syncthreads();
    }
    float mean = red[0] * (1.0f / Dc);
    __syncthreads();
    red[tid] = s2; __syncthreads();
    for (int off = 128; off > 0; off >>= 1) {
        if (tid < off) red[tid] += red[tid + off];
        __syncthreads();
    }
    float var  = red[0] * (1.0f / Dc) - mean * mean;
    float rstd = rsqrtf(var + 1e-5f);
    for (int i = tid; i < Dc; i += 256) {
        float v = (xp[i] - mean) * rstd * w[i] + b[i];
        if (outF) outF[(size_t)row * Dc + i] = v;
        if (outB) outB[(size_t)row * Dc + i] = __float2bfloat16(v);
    }
}

// ---------------------------------------------------------------------------
// Weight transpose + bf16 convert: W [K][srcN] f32 -> Wt [dstN][K] bf16,
// rows >= srcN zero-filled. Grid (dstN/32, K/32), block 256.
// ---------------------------------------------------------------------------
__global__ __launch_bounds__(256) void convw_kernel(const float* __restrict__ W,
                                                    __hip_bfloat16* __restrict__ Wt,
                                                    int K, int srcN) {
    __shared__ float t[32][33];
    int n0 = blockIdx.x * 32, k0 = blockIdx.y * 32;
    int tx = threadIdx.x & 31, ty = threadIdx.x >> 5;
    #pragma unroll
    for (int j = 0; j < 4; j++) {
        int k = k0 + ty + j * 8, n = n0 + tx;
        t[ty + j * 8][tx] = (n < srcN) ? W[(size_t)k * srcN + n] : 0.f;
    }
    __syncthreads();
    #pragma unroll
    for (int j = 0; j < 4; j++) {
        int n = n0 + ty + j * 8, k = k0 + tx;
        Wt[(size_t)n * K + k] = __float2bfloat16(t[tx][ty + j * 8]);
    }
}

__global__ void bcat_kernel(const float* __restrict__ bq, const float* __restrict__ bk,
                            const float* __restrict__ bv, float* __restrict__ o) {
    int i = blockIdx.x * 256 + threadIdx.x;
    if (i < QKVN)
        o[i] = (i < Dc) ? bq[i] : (i < 2 * Dc) ? bk[i - Dc] : bv[i - 2 * Dc];
}

// ---------------------------------------------------------------------------
// 128x128 bf16 MFMA GEMM (m97 structure) for N==1024 shapes (o-proj, mlp2):
// 256-block supertile grid keeps all 256 CUs busy at small N.
// ---------------------------------------------------------------------------
__global__ __launch_bounds__(256) void bgemm_kernel(
    const __hip_bfloat16* __restrict__ A,
    const __hip_bfloat16* __restrict__ Bt,
    const float* __restrict__ bias,
    const float* __restrict__ Cin,
    float* __restrict__ outF,
    __hip_bfloat16* __restrict__ outB,
    int N, int K, int act) {
    __shared__ __align__(16) __hip_bfloat16 As[128 * 32];
    __shared__ __align__(16) __hip_bfloat16 Bs[128 * 32];
    const int tid = threadIdx.x;
    const int bid = blockIdx.x;
    const int sup = bid >> 8, wblk = bid & 255;
    const int rowBase = (wblk & 31) * 128;
    const int colBase = (sup * 8 + (wblk >> 5)) * 128;
    const int w = tid >> 6, lane = tid & 63;
    const int wm = w >> 1, wn = w & 1;
    const int quad = lane >> 4, l16 = lane & 15;

    f32x4 acc[4][4];
    #pragma unroll
    for (int i = 0; i < 4; i++)
        #pragma unroll
        for (int j = 0; j < 4; j++) acc[i][j] = (f32x4){0.f, 0.f, 0.f, 0.f};

    const __hip_bfloat16* a0 = A  + (size_t)(rowBase + (tid >> 2)) * K + (tid & 3) * 8;
    const __hip_bfloat16* b0 = Bt + (size_t)(colBase + (tid >> 2)) * K + (tid & 3) * 8;
    const size_t rstep = (size_t)64 * K;
    __hip_bfloat16* lA = As + tid * 8;
    __hip_bfloat16* lB = Bs + tid * 8;

    for (int k0 = 0; k0 < K; k0 += 32) {
        __syncthreads();
        gl2lds16(a0 + k0,         lA);
        gl2lds16(a0 + k0 + rstep, lA + 2048);
        gl2lds16(b0 + k0,         lB);
        gl2lds16(b0 + k0 + rstep, lB + 2048);
        __syncthreads();

        short8 af[4], bf[4];
        #pragma unroll
        for (int i = 0; i < 4; i++) {
            af[i] = *(const short8*)(As + (wm * 64 + i * 16 + l16) * 32 + quad * 8);
            bf[i] = *(const short8*)(Bs + (wn * 64 + i * 16 + l16) * 32 + quad * 8);
        }
        #pragma unroll
        for (int i = 0; i < 4; i++)
            #pragma unroll
            for (int j = 0; j < 4; j++)
                acc[i][j] = __builtin_amdgcn_mfma_f32_16x16x32_bf16(af[i], bf[j], acc[i][j], 0, 0, 0);
    }

    #pragma unroll
    for (int i = 0; i < 4; i++) {
        #pragma unroll
        for (int j = 0; j < 4; j++) {
            int col = colBase + wn * 64 + j * 16 + l16;
            float bb = bias ? bias[col] : 0.f;
            #pragma unroll
            for (int r = 0; r < 4; r++) {
                int row = rowBase + wm * 64 + i * 16 + quad * 4 + r;
                float v = acc[i][j][r] + bb;
                if (Cin) v += Cin[(size_t)row * N + col];
                if (act) v = fast_gelu(v);
                if (outF) outF[(size_t)row * N + col] = v;
                if (outB) outB[(size_t)row * N + col] = __float2bfloat16(v);
            }
        }
    }
}

// ---------------------------------------------------------------------------
// 256x256-tile bf16 MFMA GEMM, BK=64, 8 waves (2M x 4N), double-buffered LDS
// with one-tile-ahead prefetch (T3-minimum: STAGE next -> compute cur ->
// __syncthreads, so HBM/L2 latency hides under ~600cy of MFMA per K-tile).
// LDS XOR-swizzle (chunk ^= row&7) via pre-swizzled global source (m173
// pattern) makes the stride-128B ds_read_b128 conflict-free.
// Grid: nSup*64 blocks; supertile = 4 col-tiles x 16 row-tiles (L2-sized).
// M == 4096; N mult of 256 (NCT col-tiles, guard for partial supertiles).
// ---------------------------------------------------------------------------
__global__ __launch_bounds__(512, 2) void bgemm256_kernel(
    const __hip_bfloat16* __restrict__ A,
    const __hip_bfloat16* __restrict__ Bt,
    const float* __restrict__ bias,
    const float* __restrict__ Cin,
    float* __restrict__ outF,
    __hip_bfloat16* __restrict__ outB,
    int N, int K, int act, int NCT) {
    __shared__ __align__(16) __hip_bfloat16 As[2][256 * 64];   // 64 KB
    __shared__ __align__(16) __hip_bfloat16 Bs[2][256 * 64];   // 64 KB
    const int tid = threadIdx.x;
    const int bid = blockIdx.x;
    const int sup = bid >> 6, wblk = bid & 63;
    const int colT = sup * 4 + (wblk >> 4);
    if (colT >= NCT) return;                   // uniform exit (partial supertile)
    const int rowBase = (wblk & 15) * 256;
    const int colBase = colT * 256;
    const int w = tid >> 6, lane = tid & 63;
    const int wm = w >> 2, wn = w & 3;
    const int quad = lane >> 4, l16 = lane & 15;

    f32x4 acc[8][4];
    #pragma unroll
    for (int i = 0; i < 8; i++)
        #pragma unroll
        for (int n = 0; n < 4; n++) acc[i][n] = (f32x4){0.f, 0.f, 0.f, 0.f};

    // staging: 512 thr x 16B = 8KB per instr = 64 rows x 64 cols; 4 instrs per
    // matrix. Source chunk pre-swizzled so linear LDS == swizzled layout.
    const int srow = tid >> 3;                 // 0..63
    const int swz  = (tid & 7) ^ (srow & 7);   // chunk ^ (row&7)
    const __hip_bfloat16* aS = A  + (size_t)(rowBase + srow) * K + swz * 8;
    const __hip_bfloat16* bS = Bt + (size_t)(colBase + srow) * K + swz * 8;
    const size_t jstep = (size_t)64 * K;

    const int nt = K >> 6;
    // prologue: stage tile 0 into buf 0
    #pragma unroll
    for (int j = 0; j < 4; j++) gl2lds16(aS + j * jstep, &As[0][j * 4096 + tid * 8]);
    #pragma unroll
    for (int j = 0; j < 4; j++) gl2lds16(bS + j * jstep, &Bs[0][j * 4096 + tid * 8]);
    __syncthreads();

    for (int t = 0; t < nt; t++) {
        // issue next tile's stage into the other buffer (overlaps compute)
        if (t + 1 < nt) {
            const int nb = (t + 1) & 1;
            const int k0 = (t + 1) << 6;
            #pragma unroll
            for (int j = 0; j < 4; j++) gl2lds16(aS + j * jstep + k0, &As[nb][j * 4096 + tid * 8]);
            #pragma unroll
            for (int j = 0; j < 4; j++) gl2lds16(bS + j * jstep + k0, &Bs[nb][j * 4096 + tid * 8]);
        }
        const __hip_bfloat16* as = As[t & 1];
        const __hip_bfloat16* bs = Bs[t & 1];
        #pragma unroll
        for (int ks = 0; ks < 2; ks++) {
            short8 bf[4], af[8];
            #pragma unroll
            for (int n = 0; n < 4; n++) {
                int row = wn * 64 + n * 16 + l16;
                bf[n] = *(const short8*)(bs + row * 64 + (((ks * 4 + quad) ^ (row & 7)) << 3));
            }
            #pragma unroll
            for (int i = 0; i < 8; i++) {
                int row = wm * 128 + i * 16 + l16;
                af[i] = *(const short8*)(as + row * 64 + (((ks * 4 + quad) ^ (row & 7)) << 3));
            }
            #pragma unroll
            for (int i = 0; i < 8; i++)
                #pragma unroll
                for (int n = 0; n < 4; n++)
                    acc[i][n] = __builtin_amdgcn_mfma_f32_16x16x32_bf16(af[i], bf[n], acc[i][n], 0, 0, 0);
        }
        __syncthreads();   // drains vmcnt: next tile landed; all waves done with cur
    }

    #pragma unroll
    for (int i = 0; i < 8; i++) {
        #pragma unroll
        for (int n = 0; n < 4; n++) {
            int col = colBase + wn * 64 + n * 16 + l16;
            float bb = bias ? bias[col] : 0.f;
            #pragma unroll
            for (int r = 0; r < 4; r++) {
                int row = rowBase + wm * 128 + i * 16 + quad * 4 + r;
                float v = acc[i][n][r] + bb;
                if (Cin) v += Cin[(size_t)row * N + col];
                if (act) v = fast_gelu(v);
                if (outF) outF[(size_t)row * N + col] = v;
                if (outB) outB[(size_t)row * N + col] = __float2bfloat16(v);
            }
        }
    }
}

// ---------------------------------------------------------------------------
// Head GEMM on the 256^2 prefetch core, fused per-row partial LSE over the
// block's 256 vocab cols + target-logit capture. Partials [NVT][Mr].
// ---------------------------------------------------------------------------
__global__ __launch_bounds__(512, 2) void headgemm256_kernel(
    const __hip_bfloat16* __restrict__ A,
    const __hip_bfloat16* __restrict__ Bt,
    const int* __restrict__ targets,
    float* __restrict__ pmax, float* __restrict__ psum,
    float* __restrict__ tlog) {
    __shared__ __align__(16) __hip_bfloat16 As[2][256 * 64];
    __shared__ __align__(16) __hip_bfloat16 Bs[2][256 * 64];
    __shared__ float pmW[4][256], psW[4][256];
    __shared__ int tg[256];
    const int tid = threadIdx.x;
    const int bid = blockIdx.x;
    const int sup = bid >> 6, wblk = bid & 63;
    const int colT = sup * 4 + (wblk >> 4);
    if (colT >= NVT) return;
    const int rowBase = (wblk & 15) * 256;
    const int colBase = colT * 256;
    const int K = Dc;
    const int w = tid >> 6, lane = tid & 63;
    const int wm = w >> 2, wn = w & 3;
    const int quad = lane >> 4, l16 = lane & 15;

    if (tid < 256) tg[tid] = targets[rowBase + tid];

    f32x4 acc[8][4];
    #pragma unroll
    for (int i = 0; i < 8; i++)
        #pragma unroll
        for (int n = 0; n < 4; n++) acc[i][n] = (f32x4){0.f, 0.f, 0.f, 0.f};

    const int srow = tid >> 3;
    const int swz  = (tid & 7) ^ (srow & 7);
    const __hip_bfloat16* aS = A  + (size_t)(rowBase + srow) * K + swz * 8;
    const __hip_bfloat16* bS = Bt + (size_t)(colBase + srow) * K + swz * 8;
    const size_t jstep = (size_t)64 * K;

    const int nt = K >> 6;
    #pragma unroll
    for (int j = 0; j < 4; j++) gl2lds16(aS + j * jstep, &As[0][j * 4096 + tid * 8]);
    #pragma unroll
    for (int j = 0; j < 4; j++) gl2lds16(bS + j * jstep, &Bs[0][j * 4096 + tid * 8]);
    __syncthreads();

    for (int t = 0; t < nt; t++) {
        if (t + 1 < nt) {
            const int nb = (t + 1) & 1;
            const int k0 = (t + 1) << 6;
            #pragma unroll
            for (int j = 0; j < 4; j++) gl2lds16(aS + j * jstep + k0, &As[nb][j * 4096 + tid * 8]);
            #pragma unroll
            for (int j = 0; j < 4; j++) gl2lds16(bS + j * jstep + k0, &Bs[nb][j * 4096 + tid * 8]);
        }
        const __hip_bfloat16* as = As[t & 1];
        const __hip_bfloat16* bs = Bs[t & 1];
        #pragma unroll
        for (int ks = 0; ks < 2; ks++) {
            short8 bf[4], af[8];
            #pragma unroll
            for (int n = 0; n < 4; n++) {
                int row = wn * 64 + n * 16 + l16;
                bf[n] = *(const short8*)(bs + row * 64 + (((ks * 4 + quad) ^ (row & 7)) << 3));
            }
            #pragma unroll
            for (int i = 0; i < 8; i++) {
                int row = wm * 128 + i * 16 + l16;
                af[i] = *(const short8*)(as + row * 64 + (((ks * 4 + quad) ^ (row & 7)) << 3));
            }
            #pragma unroll
            for (int i = 0; i < 8; i++)
                #pragma unroll
                for (int n = 0; n < 4; n++)
                    acc[i][n] = __builtin_amdgcn_mfma_f32_16x16x32_bf16(af[i], bf[n], acc[i][n], 0, 0, 0);
        }
        __syncthreads();
    }

    // LSE epilogue: cheap max butterfly, one local exp pass, add butterfly.
    #pragma unroll
    for (int i = 0; i < 8; i++) {
        #pragma unroll
        for (int r = 0; r < 4; r++) {
            int rib = wm * 128 + i * 16 + quad * 4 + r;
            int tgt = tg[rib];
            float vals[4];
            float m = -1e30f;
            #pragma unroll
            for (int n = 0; n < 4; n++) {
                int col = colBase + wn * 64 + n * 16 + l16;
                float v = acc[i][n][r];
                bool ok = (col < Vc);
                if (ok && col == tgt) tlog[rowBase + rib] = v;
                vals[n] = ok ? v : -1e30f;
                m = fmaxf(m, vals[n]);
            }
            #pragma unroll
            for (int d = 1; d < 16; d <<= 1)
                m = fmaxf(m, __shfl_xor(m, d, 64));
            float s = 0.f;
            #pragma unroll
            for (int n = 0; n < 4; n++) s += __expf(vals[n] - m);
            #pragma unroll
            for (int d = 1; d < 16; d <<= 1)
                s += __shfl_xor(s, d, 64);
            if (l16 == 0) { pmW[wn][rib] = m; psW[wn][rib] = s; }
        }
    }
    __syncthreads();
    if (tid < 256) {
        float m = pmW[0][tid], s = psW[0][tid];
        lse_combine(m, s, pmW[1][tid], psW[1][tid]);
        lse_combine(m, s, pmW[2][tid], psW[2][tid]);
        lse_combine(m, s, pmW[3][tid], psW[3][tid]);
        pmax[(size_t)colT * Mr + rowBase + tid] = m;
        psum[(size_t)colT * Mr + rowBase + tid] = s;
    }
}

__global__ __launch_bounds__(256) void head_reduce_kernel(
    const float* __restrict__ pmax, const float* __restrict__ psum,
    const float* __restrict__ tlog, float* __restrict__ nll) {
    __shared__ float rm[256], rs[256];
    int row = blockIdx.x;
    int tid = threadIdx.x;
    float m = -1e30f, s = 0.f;
    for (int t = tid; t < NVT; t += 256)
        lse_combine(m, s, pmax[(size_t)t * Mr + row], psum[(size_t)t * Mr + row]);
    rm[tid] = m; rs[tid] = s; __syncthreads();
    for (int off = 128; off > 0; off >>= 1) {
        if (tid < off) {
            float mm = rm[tid], ss = rs[tid];
            lse_combine(mm, ss, rm[tid + off], rs[tid + off]);
            rm[tid] = mm; rs[tid] = ss;
        }
        __syncthreads();
    }
    if (tid == 0) nll[row] = rm[0] + logf(rs[0]) - tlog[row];
}

// ---------------------------------------------------------------------------
// RoPE + bf16 split: reads fused bf16 qkv [Mr][3072]; writes
// qb [B*H][S][64] (pre-scaled by 1/sqrt(DH)) and kb [B*H][S][64].
// ---------------------------------------------------------------------------
__global__ void ropecvt_kernel(const __hip_bfloat16* __restrict__ qkvb,
                               __hip_bfloat16* __restrict__ qb,
                               __hip_bfloat16* __restrict__ kb) {
    int p = blockIdx.x * blockDim.x + threadIdx.x;
    if (p >= Mr * Hc * 32) return;
    int j    = p & 31;
    int h    = (p >> 5) & (Hc - 1);
    int srow = p >> 9;
    int s    = srow & (Sc - 1);
    int b    = srow >> 11;
    float inv = powf(10000.0f, -(float)(2 * j) * (1.0f / 64.0f));
    float fr  = (float)s * inv;
    float c = cosf(fr), sn = sinf(fr);
    size_t base = (size_t)srow * QKVN + h * DHc;
    size_t o = ((size_t)(b * Hc + h) * Sc + s) * DHc;
    float q1 = __bfloat162float(qkvb[base + j]);
    float q2 = __bfloat162float(qkvb[base + j + 32]);
    qb[o + j]      = __float2bfloat16((q1 * c - q2 * sn) * 0.125f);
    qb[o + j + 32] = __float2bfloat16((q2 * c + q1 * sn) * 0.125f);
    float k1 = __bfloat162float(qkvb[base + Dc + j]);
    float k2 = __bfloat162float(qkvb[base + Dc + j + 32]);
    kb[o + j]      = __float2bfloat16(k1 * c - k2 * sn);
    kb[o + j + 32] = __float2bfloat16(k2 * c + k1 * sn);
}

// ---------------------------------------------------------------------------
// V transpose: fused qkv [Mr][3072] bf16 -> vtb [B*H][64][S] bf16.
// ---------------------------------------------------------------------------
__global__ __launch_bounds__(256) void vt_kernel(const __hip_bfloat16* __restrict__ qkvb,
                                                 __hip_bfloat16* __restrict__ vtb) {
    __shared__ float t[32][33];
    int s0 = blockIdx.x * 32, d0 = blockIdx.y * 32;
    int bh = blockIdx.z;
    int b = bh >> 4, h = bh & (Hc - 1);
    int tx = threadIdx.x & 31, ty = threadIdx.x >> 5;
    #pragma unroll
    for (int jj = 0; jj < 4; jj++) {
        int s = s0 + ty + jj * 8;
        t[ty + jj * 8][tx] = __bfloat162float(
            qkvb[((size_t)(b * Sc + s)) * QKVN + 2 * Dc + h * DHc + d0 + tx]);
    }
    __syncthreads();
    #pragma unroll
    for (int jj = 0; jj < 4; jj++) {
        int d = d0 + ty + jj * 8;
        vtb[((size_t)bh * DHc + d) * Sc + s0 + tx] = __float2bfloat16(t[tx][ty + jj * 8]);
    }
}

// ---------------------------------------------------------------------------
// Flash attention, MFMA (verified round 1). One block per (b,h,qtile).
// ---------------------------------------------------------------------------
__global__ __launch_bounds__(256) void attn_mfma_kernel(
    const __hip_bfloat16* __restrict__ qb,
    const __hip_bfloat16* __restrict__ kb,
    const __hip_bfloat16* __restrict__ vtb,
    __hip_bfloat16* __restrict__ ob) {
    __shared__ __align__(16) __hip_bfloat16 Ks[128 * 64];
    __shared__ __align__(16) __hip_bfloat16 Vts[64 * 128];
    __shared__ __align__(16) __hip_bfloat16 Ps[128 * 128];

    const int tid  = threadIdx.x;
    const int idx  = blockIdx.x;
    const int qt   = (NQT - 1) - (idx >> 5);
    const int bh   = idx & 31;
    const int b    = bh >> 4, h = bh & (Hc - 1);
    const int w    = tid >> 6, lane = tid & 63;
    const int quad = lane >> 4, l16 = lane & 15;
    const int sz   = l16 & 7;

    const __hip_bfloat16* kb_bh = kb  + (size_t)bh * Sc * DHc;
    const __hip_bfloat16* vt_bh = vtb + (size_t)bh * DHc * Sc;

    short8 afq[2][2];
    {
        const __hip_bfloat16* qp =
            qb + ((size_t)bh * Sc + qt * 128 + w * 32 + l16) * DHc;
        #pragma unroll
        for (int i = 0; i < 2; i++)
            #pragma unroll
            for (int dc = 0; dc < 2; dc++)
                afq[i][dc] = *(const short8*)(qp + i * 16 * DHc + (dc * 4 + quad) * 8);
    }

    f32x4 oacc[2][4];
    float m[2][4], lsum[2][4];
    #pragma unroll
    for (int i = 0; i < 2; i++)
        #pragma unroll
        for (int dt = 0; dt < 4; dt++) oacc[i][dt] = (f32x4){0.f, 0.f, 0.f, 0.f};
    #pragma unroll
    for (int i = 0; i < 2; i++)
        #pragma unroll
        for (int r = 0; r < 4; r++) { m[i][r] = -1e30f; lsum[i][r] = 0.f; }

    for (int kt = 0; kt <= qt; ++kt) {
        __syncthreads();
        #pragma unroll
        for (int p = 0; p < 4; p++) {
            int k = p * 32 + (tid >> 3);
            gl2lds16(kb_bh + ((size_t)(kt * 128 + k)) * DHc + (((tid & 7) ^ (k & 7)) << 3),
                     Ks + p * 2048 + tid * 8);
        }
        #pragma unroll
        for (int p = 0; p < 4; p++) {
            int d = p * 16 + (tid >> 4);
            gl2lds16(vt_bh + (size_t)d * Sc + kt * 128 + (((tid & 15) ^ (d & 7)) << 3),
                     Vts + p * 2048 + tid * 8);
        }
        __syncthreads();

        f32x4 sacc[2][8];
        #pragma unroll
        for (int i = 0; i < 2; i++)
            #pragma unroll
            for (int j = 0; j < 8; j++) sacc[i][j] = (f32x4){0.f, 0.f, 0.f, 0.f};
        #pragma unroll
        for (int j = 0; j < 8; j++) {
            const __hip_bfloat16* kp = Ks + (j * 16 + l16) * DHc;
            short8 bk0 = *(const short8*)(kp + ((quad ^ sz) << 3));
            short8 bk1 = *(const short8*)(kp + (((4 + quad) ^ sz) << 3));
            #pragma unroll
            for (int i = 0; i < 2; i++) {
                sacc[i][j] = __builtin_amdgcn_mfma_f32_16x16x32_bf16(afq[i][0], bk0, sacc[i][j], 0, 0, 0);
                sacc[i][j] = __builtin_amdgcn_mfma_f32_16x16x32_bf16(afq[i][1], bk1, sacc[i][j], 0, 0, 0);
            }
        }

        const bool diag = (kt == qt);
        #pragma unroll
        for (int i = 0; i < 2; i++) {
            #pragma unroll
            for (int r = 0; r < 4; r++) {
                int rowq = w * 32 + i * 16 + quad * 4 + r;
                float rm = -1e30f;
                #pragma unroll
                for (int j = 0; j < 8; j++) {
                    float v = sacc[i][j][r];
                    if (diag && (j * 16 + l16 > rowq)) v = -1e30f;
                    sacc[i][j][r] = v;
                    rm = fmaxf(rm, v);
                }
                #pragma unroll
                for (int dlt = 1; dlt < 16; dlt <<= 1)
                    rm = fmaxf(rm, __shfl_xor(rm, dlt, 64));
                float mn = fmaxf(m[i][r], rm);
                float fm = __expf(m[i][r] - mn);
                m[i][r] = mn;
                float rs = 0.f;
                #pragma unroll
                for (int j = 0; j < 8; j++) {
                    float pe = __expf(sacc[i][j][r] - mn);
                    sacc[i][j][r] = pe;
                    rs += pe;
                }
                #pragma unroll
                for (int dlt = 1; dlt < 16; dlt <<= 1)
                    rs += __shfl_xor(rs, dlt, 64);
                lsum[i][r] = lsum[i][r] * fm + rs;
                #pragma unroll
                for (int dt = 0; dt < 4; dt++) oacc[i][dt][r] *= fm;
            }
        }

        #pragma unroll
        for (int i = 0; i < 2; i++) {
            #pragma unroll
            for (int r = 0; r < 4; r++) {
                int Q = w * 32 + i * 16 + quad * 4 + r;
                int rowoff = Q * 128;
                int swz = (Q & 7) << 3;
                #pragma unroll
                for (int j = 0; j < 8; j++)
                    Ps[rowoff + ((j * 16 + l16) ^ swz)] = __float2bfloat16(sacc[i][j][r]);
            }
        }

        #pragma unroll
        for (int kc = 0; kc < 4; kc++) {
            int ch = ((kc * 4 + quad) ^ sz) << 3;
            short8 ap[2], bv[4];
            #pragma unroll
            for (int i = 0; i < 2; i++)
                ap[i] = *(const short8*)(Ps + (w * 32 + i * 16 + l16) * 128 + ch);
            #pragma unroll
            for (int dt = 0; dt < 4; dt++)
                bv[dt] = *(const short8*)(Vts + (dt * 16 + l16) * 128 + ch);
            #pragma unroll
            for (int i = 0; i < 2; i++)
                #pragma unroll
                for (int dt = 0; dt < 4; dt++)
                    oacc[i][dt] = __builtin_amdgcn_mfma_f32_16x16x32_bf16(ap[i], bv[dt], oacc[i][dt], 0, 0, 0);
        }
    }

    #pragma unroll
    for (int i = 0; i < 2; i++) {
        #pragma unroll
        for (int r = 0; r < 4; r++) {
            float inv = 1.0f / lsum[i][r];
            int s = qt * 128 + w * 32 + i * 16 + quad * 4 + r;
            size_t base = ((size_t)b * Sc + s) * Dc + h * DHc;
            #pragma unroll
            for (int dt = 0; dt < 4; dt++)
                ob[base + dt * 16 + l16] = __float2bfloat16(oacc[i][dt][r] * inv);
        }
    }
}

__global__ __launch_bounds__(256) void loss_kernel(const float* __restrict__ nll,
                                                   float* __restrict__ out) {
    __shared__ float red[256];
    int tid = threadIdx.x;
    float s = 0.f;
    for (int i = tid; i < Mr; i += 256) s += nll[i];
    red[tid] = s; __syncthreads();
    for (int off = 128; off > 0; off >>= 1) {
        if (tid < off) red[tid] += red[tid + off];
        __syncthreads();
    }
    if (tid == 0) out[0] = red[0] * (1.0f / Mr);
}

// ---------------------------------------------------------------------------
// Host launch
// ---------------------------------------------------------------------------
extern "C" void kernel_launch(void* const* d_in, const int* in_sizes, int n_in,
                              void* d_out, int out_size, void* d_ws, size_t ws_size,
                              hipStream_t stream) {
    const int*   tokens   = (const int*)  d_in[0];
    const int*   targets  = (const int*)  d_in[1];
    const float* word_emb = (const float*)d_in[2];
    const float* pos_emb  = (const float*)d_in[3];
    const float* ln1_w    = (const float*)d_in[4];
    const float* ln1_b    = (const float*)d_in[5];
    const float* wq       = (const float*)d_in[6];
    const float* bq       = (const float*)d_in[7];
    const float* wk       = (const float*)d_in[8];
    const float* bk       = (const float*)d_in[9];
    const float* wv       = (const float*)d_in[10];
    const float* bv       = (const float*)d_in[11];
    const float* wo       = (const float*)d_in[12];
    const float* bo       = (const float*)d_in[13];
    const float* ln2_w    = (const float*)d_in[14];
    const float* ln2_b    = (const float*)d_in[15];
    const float* w1       = (const float*)d_in[16];
    const float* b1       = (const float*)d_in[17];
    const float* w2       = (const float*)d_in[18];
    const float* b2       = (const float*)d_in[19];
    const float* post_w   = (const float*)d_in[20];
    const float* post_b   = (const float*)d_in[21];
    const float* lnf_w    = (const float*)d_in[22];
    const float* lnf_b    = (const float*)d_in[23];
    const float* head_w   = (const float*)d_in[24];

    // Workspace layout (~240 MB)
    float* cur = (float*)d_ws;
    float* x    = cur; cur += (size_t)Mr * Dc;        // 16 MB
    float* nll  = cur; cur += Mr;
    float* tlog = cur; cur += Mr;
    float* bqkv = cur; cur += QKVN;
    float* pmax = cur; cur += (size_t)NVT * Mr;       // 3.2 MB
    float* psum = cur; cur += (size_t)NVT * Mr;       // 3.2 MB
    __hip_bfloat16* bcur = (__hip_bfloat16*)cur;
    __hip_bfloat16* hb     = bcur; bcur += (size_t)Mr * Dc;     // 8 MB
    __hip_bfloat16* ob     = bcur; bcur += (size_t)Mr * Dc;     // 8 MB
    __hip_bfloat16* midb   = bcur; bcur += (size_t)Mr * Fc;     // 32 MB
    __hip_bfloat16* qkvb   = bcur; bcur += (size_t)Mr * QKVN;   // 24 MB
    __hip_bfloat16* qb     = bcur; bcur += (size_t)Mr * Dc;     // 8 MB
    __hip_bfloat16* kbuf   = bcur; bcur += (size_t)Mr * Dc;     // 8 MB
    __hip_bfloat16* Wqkv_t = bcur; bcur += (size_t)QKVN * Dc;   // 6 MB
    __hip_bfloat16* Wo_t   = bcur; bcur += (size_t)Dc * Dc;     // 2 MB
    __hip_bfloat16* W1_t   = bcur; bcur += (size_t)Fc * Dc;     // 8 MB
    __hip_bfloat16* W2_t   = bcur; bcur += (size_t)Dc * Fc;     // 8 MB
    __hip_bfloat16* Wh_t   = bcur; bcur += (size_t)Vpad * Dc;   // 103 MB
    __hip_bfloat16* vtb = midb;   // alias: vtb live only vt_kernel..attn

    dim3 blk(256);
    dim3 blk512(512);

    embed_kernel<<<Mr, blk, 0, stream>>>(tokens, word_emb, pos_emb, x);
    convw_kernel<<<dim3(Vpad / 32, Dc / 32), blk, 0, stream>>>(head_w, Wh_t, Dc, Vc);

    for (int l = 0; l < Lc; l++) {
        convw_kernel<<<dim3(Dc / 32, Dc / 32), blk, 0, stream>>>(wq + (size_t)l * Dc * Dc, Wqkv_t, Dc, Dc);
        convw_kernel<<<dim3(Dc / 32, Dc / 32), blk, 0, stream>>>(wk + (size_t)l * Dc * Dc, Wqkv_t + (size_t)Dc * Dc, Dc, Dc);
        convw_kernel<<<dim3(Dc / 32, Dc / 32), blk, 0, stream>>>(wv + (size_t)l * Dc * Dc, Wqkv_t + (size_t)2 * Dc * Dc, Dc, Dc);
        bcat_kernel<<<QKVN / 256, blk, 0, stream>>>(bq + l * Dc, bk + l * Dc, bv + l * Dc, bqkv);

        ln_kernel<<<Mr, blk, 0, stream>>>(x, ln1_w + l * Dc, ln1_b + l * Dc, nullptr, hb);
        bgemm256_kernel<<<(QKVN / 1024) * 64, blk512, 0, stream>>>(
            hb, Wqkv_t, bqkv, nullptr, nullptr, qkvb, QKVN, Dc, 0, QKVN / 256);
        ropecvt_kernel<<<(Mr * Hc * 32) / 256, blk, 0, stream>>>(qkvb, qb, kbuf);
        vt_kernel<<<dim3(Sc / 32, DHc / 32, Bc * Hc), blk, 0, stream>>>(qkvb, vtb);
        attn_mfma_kernel<<<Bc * Hc * NQT, blk, 0, stream>>>(qb, kbuf, vtb, ob);

        convw_kernel<<<dim3(Dc / 32, Dc / 32), blk, 0, stream>>>(wo + (size_t)l * Dc * Dc, Wo_t, Dc, Dc);
        bgemm_kernel<<<(Dc / 1024) * 256, blk, 0, stream>>>(
            ob, Wo_t, bo + l * Dc, x, x, nullptr, Dc, Dc, 0);

        ln_kernel<<<Mr, blk, 0, stream>>>(x, ln2_w + l * Dc, ln2_b + l * Dc, nullptr, hb);
        convw_kernel<<<dim3(Fc / 32, Dc / 32), blk, 0, stream>>>(w1 + (size_t)l * Dc * Fc, W1_t, Dc, Fc);
        bgemm256_kernel<<<(Fc / 1024) * 64, blk512, 0, stream>>>(
            hb, W1_t, b1 + l * Fc, nullptr, nullptr, midb, Fc, Dc, 1, Fc / 256);
        convw_kernel<<<dim3(Dc / 32, Fc / 32), blk, 0, stream>>>(w2 + (size_t)l * Fc * Dc, W2_t, Fc, Dc);
        bgemm_kernel<<<(Dc / 1024) * 256, blk, 0, stream>>>(
            midb, W2_t, b2 + l * Dc, x, x, nullptr, Dc, Fc, 0);

        if (l == Lc - 1)
            ln_kernel<<<Mr, blk, 0, stream>>>(x, post_w, post_b, x, nullptr);
    }

    ln_kernel<<<Mr, blk, 0, stream>>>(x, lnf_w, lnf_b, nullptr, hb);
    headgemm256_kernel<<<((NVT + 3) / 4) * 64, blk512, 0, stream>>>(
        hb, Wh_t, targets, pmax, psum, tlog);
    head_reduce_kernel<<<Mr, blk, 0, stream>>>(pmax, psum, tlog, nll);
    loss_kernel<<<1, blk, 0, stream>>>(nll, (float*)d_out);
}